// Round 7
// baseline (195.262 us; speedup 1.0000x reference)
//
#include <hip/hip_runtime.h>
#include <stdint.h>

// ---------------------------------------------------------------------------
// Fused attention: out = dropout(softmax(0.5 * x1 @ x2^T), p=0.2, jax key 42) @ x2
// B=8, M=N=2048, D=128, fp32 in/out. bf16 MFMA (16x16x32), bitwise JAX threefry
// (partitionable form: bits = h0^h1 of threefry((0,42),(0,flat_idx))).
//
// R11: decouple the threefry from the attention pipeline. Evidence chain:
//  - R10: occupancy 28->49% with no spill, time FLAT, VALUBusy pinned ~73%
//    -> VALU-execution-bound; scheduling/occupancy moves are exhausted.
//  - threefry = ~72 VALU ops/elem = ~31us chip floor; fused it runs at 73%
//    packing and serializes against MFMA/DS phases.
// -> (1) maskgen_kernel: dedicated threefry kernel, 64 dropout decisions per
//        wave-iter bit-packed via __ballot (v_cmp = free 64-way packing);
//        4MB mask in d_ws; near-100% VALU packing, ~35us.
//    (2) attn5_kernel: attn4 with the inline threefry replaced by a 1-dword
//        mask load per tile + 3 VALU/elem bit-test -> lean MFMA/exp2 kernel.
//    Same XCD b-swizzle in both: each batch's 512KB mask slice is produced
//    and consumed on the same XCD's L2.
// Mask layout: MW[(b*2048+row)*64 + j] covers cols 32j..32j+31 of row, bit =
// col%32. maskgen: idx = b*2^22+row*2048+cb*64+lane, ballot bit lane = col.
// attn5: word j = w*8+tt, bit t*16+4g+r. Bit-exact by construction.
// Fallbacks: ws>=8MB -> R10 attn4 (92us proven); else R4 attn (107us).
// ---------------------------------------------------------------------------

typedef __bf16 bf16x8 __attribute__((ext_vector_type(8)));
typedef float f32x4 __attribute__((ext_vector_type(4)));

__device__ __forceinline__ uint32_t rotl32(uint32_t x, uint32_t r) {
  return (x << r) | (x >> (32u - r));   // -> v_alignbit_b32
}

// JAX threefry2x32 with key (0, 42)
__device__ __forceinline__ void threefry2x32_k42(uint32_t in0, uint32_t in1,
                                                 uint32_t& o0, uint32_t& o1) {
  const uint32_t ks0 = 0u;
  const uint32_t ks1 = 42u;
  const uint32_t ks2 = 0x1BD11BDAu ^ 0u ^ 42u;
  uint32_t x0 = in0 + ks0;
  uint32_t x1 = in1 + ks1;
#define TFR(r) { x0 += x1; x1 = rotl32(x1, r); x1 ^= x0; }
  TFR(13u) TFR(15u) TFR(26u) TFR(6u)
  x0 += ks1; x1 += ks2 + 1u;
  TFR(17u) TFR(29u) TFR(16u) TFR(24u)
  x0 += ks2; x1 += ks0 + 2u;
  TFR(13u) TFR(15u) TFR(26u) TFR(6u)
  x0 += ks0; x1 += ks1 + 3u;
  TFR(17u) TFR(29u) TFR(16u) TFR(24u)
  x0 += ks1; x1 += ks2 + 4u;
  TFR(13u) TFR(15u) TFR(26u) TFR(6u)
  x0 += ks2; x1 += ks0 + 5u;
#undef TFR
  o0 = x0; o1 = x1;
}

__device__ __forceinline__ uint32_t pack_bf16(float a, float b) {
  __bf16 ba = (__bf16)a;   // RTNE
  __bf16 bb = (__bf16)b;
  uint32_t ua = (uint32_t)__builtin_bit_cast(uint16_t, ba);
  uint32_t ub = (uint32_t)__builtin_bit_cast(uint16_t, bb);
  return ua | (ub << 16);
}

// keep iff uniform < 0.8f  <=>  bits < 6710887<<9
#define KEEP_LT 3435974144u
#define MBIAS 40.0f   // used only by the R4 fallback kernel

// ---------------------------------------------------------------------------
// Prepass: pack x2 (f32) into fragment-ordered bf16 layouts in workspace.
//   KF[((b*64+T)*8 + c*2+h)*64 + lane] (uint4):
//     A-frag for QK^T: rows n = T*32 + h*16 + l15, 8 bf16 at d = c*32+8g..+7
//   VF[((b*64+T)*8 + dt)*64 + lane] (uint4):
//     B-frag for PV: u[j] = pack(x2[T*32+8g+2j][dt*16+l15], x2[..+2j+1][..])
// Each 4MB.
// ---------------------------------------------------------------------------
__launch_bounds__(256, 4)
__global__ void prep_kernel(const float* __restrict__ x2,
                            uint4* __restrict__ KF,
                            uint4* __restrict__ VF) {
  const int tid = threadIdx.x;
  const int w = tid >> 6;        // 0..3  (= c for KF; = dt base for VF)
  const int lane = tid & 63;
  const int l15 = lane & 15;
  const int g = lane >> 4;
  const int T = blockIdx.x;      // 0..63 (32-row n-tile)
  const int b = blockIdx.y;
  const float* xb = x2 + (size_t)b * 2048 * 128;

  #pragma unroll
  for (int h = 0; h < 2; ++h) {
    const int n = T * 32 + h * 16 + l15;
    const float* p = xb + (size_t)n * 128 + w * 32 + 8 * g;
    float4 f0 = *(const float4*)(p);
    float4 f1 = *(const float4*)(p + 4);
    uint4 u;
    u.x = pack_bf16(f0.x, f0.y);
    u.y = pack_bf16(f0.z, f0.w);
    u.z = pack_bf16(f1.x, f1.y);
    u.w = pack_bf16(f1.z, f1.w);
    KF[(size_t)((b * 64 + T) * 8 + w * 2 + h) * 64 + lane] = u;
  }

  #pragma unroll
  for (int i = 0; i < 2; ++i) {
    const int dt = w + 4 * i;
    const int d = dt * 16 + l15;
    const float* p = xb + (size_t)(T * 32 + 8 * g) * 128 + d;
    uint4 u;
    u.x = pack_bf16(p[0],   p[128]);
    u.y = pack_bf16(p[256], p[384]);
    u.z = pack_bf16(p[512], p[640]);
    u.w = pack_bf16(p[768], p[896]);
    VF[(size_t)((b * 64 + T) * 8 + dt) * 64 + lane] = u;
  }
}

// ---------------------------------------------------------------------------
// Mask generation: pure threefry at max VALU packing. Each wave-iteration:
// 64 lanes compute one row x 64 cols of keep-bits; __ballot packs them into
// 64 bits; lane 0 stores 8 bytes. 2048 blocks x 4 waves x 2 rows x 32 cbs.
// b = blockIdx&7 matches the consumer's XCD swizzle (mask slice stays in
// the producing XCD's L2).
// ---------------------------------------------------------------------------
__launch_bounds__(256, 8)
__global__ void maskgen_kernel(uint32_t* __restrict__ MW) {
  const int tid = threadIdx.x;
  const int w = tid >> 6;
  const int lane = tid & 63;
  const int bid = blockIdx.x;           // 0..2047
  const int b = bid & 7;
  const int rowbase = (bid >> 3) * 8 + w * 2;

  #pragma unroll
  for (int rr = 0; rr < 2; ++rr) {
    const int row = rowbase + rr;
    const uint32_t base = (uint32_t)b * 4194304u + (uint32_t)row * 2048u +
                          (uint32_t)lane;
    uint32_t* mrow = MW + (size_t)(b * 2048 + row) * 64;
    #pragma unroll 4
    for (int cb = 0; cb < 32; ++cb) {
      uint32_t h0, h1;
      threefry2x32_k42(0u, base + (uint32_t)(cb * 64), h0, h1);
      unsigned long long bal = __ballot((h0 ^ h1) < KEEP_LT);
      if (lane == 0) {
        *(uint2*)&mrow[2 * cb] =
            make_uint2((uint32_t)bal, (uint32_t)(bal >> 32));
      }
    }
  }
}

// ---------------------------------------------------------------------------
// Main kernel: 16 m-rows per block, 8 waves each owning a 256-col N-eighth.
// Dropout = 1 mask-dword load per tile + bit tests (threefry lives in
// maskgen_kernel).
// ---------------------------------------------------------------------------
__launch_bounds__(512, 4)
__global__ void attn5_kernel(const float* __restrict__ x1,
                             const uint4* __restrict__ KF,
                             const uint4* __restrict__ VF,
                             const uint32_t* __restrict__ MW,
                             float* __restrict__ out) {
  // LDS 8832 words = 35328B -> 4 blocks/CU.
  // Main loop:  Qld [0..1024) shared Q-frags; Pb [1024..3584) 8x320 words.
  // Epilogue (aliases all): EP 8192 + EPL 640.
  __shared__ __attribute__((aligned(16))) uint32_t SMEM[8832];

  const int tid = threadIdx.x;
  const int w = __builtin_amdgcn_readfirstlane(tid >> 6);   // N-eighth 0..7
  const int lane = tid & 63;
  const int l15 = lane & 15;
  const int g = lane >> 4;
  const int id = blockIdx.y * 128 + blockIdx.x;
  const int b = id & 7;                 // XCD batch swizzle
  const int mt = id >> 3;
  const int m0 = mt * 16;
  const int t0 = (mt + w) & 7;          // per-wave tile-phase stagger

  uint32_t* Qld = &SMEM[0];
  uint32_t* PbW = &SMEM[1024 + w * 320];

  // ---- stage Q fragments to LDS once (wave 0; block-uniform) ----
  const float QSCALE = 0.5f * 1.44269504088896340736f;
  if (w == 0) {
    const float* qp_base = x1 + ((size_t)b * 2048 + m0 + l15) * 128;
    #pragma unroll
    for (int c = 0; c < 4; ++c) {
      const float* qp = qp_base + c * 32 + g * 8;
      float4 f0 = *(const float4*)(qp);
      float4 f1 = *(const float4*)(qp + 4);
      uint4 u;
      u.x = pack_bf16(f0.x * QSCALE, f0.y * QSCALE);
      u.y = pack_bf16(f0.z * QSCALE, f0.w * QSCALE);
      u.z = pack_bf16(f1.x * QSCALE, f1.y * QSCALE);
      u.w = pack_bf16(f1.z * QSCALE, f1.w * QSCALE);
      *(uint4*)&Qld[(c * 64 + lane) * 4] = u;
    }
  }
  __syncthreads();

  f32x4 o[8];
  #pragma unroll
  for (int dt = 0; dt < 8; ++dt) o[dt] = (f32x4){0.f, 0.f, 0.f, 0.f};
  float lsum = 0.f;

  const uint4* kfb = KF + (size_t)((b * 64 + w * 8) * 8) * 64 + lane;
  const uint4* vfb = VF + (size_t)((b * 64 + w * 8) * 8) * 64 + lane;
  // Mask row pointer: word (w*8+tt) of row (m0+l15); bit t*16+4g+r.
  const uint32_t* MWrow =
      MW + (size_t)(b * 2048 + m0 + l15) * 64 + w * 8;

  for (int tile = 0; tile < 8; ++tile) {
    const int tt = (t0 + tile) & 7;
    const uint4* kfp = kfb + (size_t)tt * 512;
    const uint4* vfp = vfb + (size_t)tt * 512;

    // Issue the mask load first: L2 latency hides under QK MFMAs.
    const uint32_t m32 = MWrow[tt];

    // ---- S^T = K Q^T : C/D row = n (4g+r), col = m (l15). ----
    f32x4 sa[2];
    sa[0] = (f32x4){0.f, 0.f, 0.f, 0.f};
    sa[1] = (f32x4){0.f, 0.f, 0.f, 0.f};
    __builtin_amdgcn_s_setprio(1);
    #pragma unroll
    for (int c = 0; c < 4; ++c) {
      bf16x8 qc = __builtin_bit_cast(bf16x8, *(const uint4*)&Qld[(c * 64 + lane) * 4]);
      bf16x8 k0 = __builtin_bit_cast(bf16x8, kfp[(c * 2 + 0) * 64]);
      bf16x8 k1 = __builtin_bit_cast(bf16x8, kfp[(c * 2 + 1) * 64]);
      sa[0] = __builtin_amdgcn_mfma_f32_16x16x32_bf16(k0, qc, sa[0], 0, 0, 0);
      sa[1] = __builtin_amdgcn_mfma_f32_16x16x32_bf16(k1, qc, sa[1], 0, 0, 0);
    }
    __builtin_amdgcn_s_setprio(0);

    // ---- softmax (unbiased exp2; 2^bias cancels in L) + mask bit-test +
    //      P -> Pbuf ----
    const uint32_t mshift = m32 >> (4 * g);   // bits now at t*16 + r
    #pragma unroll
    for (int t = 0; t < 2; ++t) {
      float p0 = __builtin_amdgcn_exp2f(sa[t][0]);
      float p1 = __builtin_amdgcn_exp2f(sa[t][1]);
      float p2 = __builtin_amdgcn_exp2f(sa[t][2]);
      float p3 = __builtin_amdgcn_exp2f(sa[t][3]);
      lsum += (p0 + p1) + (p2 + p3);   // denominator uses UNMASKED probs
      float q0 = ((mshift >> (t * 16 + 0)) & 1u) ? p0 : 0.0f;
      float q1 = ((mshift >> (t * 16 + 1)) & 1u) ? p1 : 0.0f;
      float q2 = ((mshift >> (t * 16 + 2)) & 1u) ? p2 : 0.0f;
      float q3 = ((mshift >> (t * 16 + 3)) & 1u) ? p3 : 0.0f;
      *(uint2*)&PbW[l15 * 20 + t * 8 + 2 * g] =
          make_uint2(pack_bf16(q0, q1), pack_bf16(q2, q3));
    }
    asm volatile("s_waitcnt lgkmcnt(0)" ::: "memory");  // in-order DS per wave
    uint4 pu = *(const uint4*)&PbW[l15 * 20 + 4 * g];   // A-frag: m=l15, k=8g+j
    bf16x8 pav = __builtin_bit_cast(bf16x8, pu);

    // ---- O += P V : V B-frags pre-permuted in VF ----
    __builtin_amdgcn_s_setprio(1);
    #pragma unroll
    for (int dt = 0; dt < 8; ++dt) {
      bf16x8 vb = __builtin_bit_cast(bf16x8, vfp[dt * 64]);
      o[dt] = __builtin_amdgcn_mfma_f32_16x16x32_bf16(pav, vb, o[dt], 0, 0, 0);
    }
    __builtin_amdgcn_s_setprio(0);
  }

  // ---- epilogue: merge 8 N-eighths in two dt-half passes (R10-verified) ----
  __syncthreads();
  float* EP = (float*)&SMEM[0];
  float* EPL = EP + 8192;
  EPL[l15 * 40 + w * 4 + g] = lsum;
  #pragma unroll
  for (int dt = 0; dt < 4; ++dt)
    #pragma unroll
    for (int r = 0; r < 4; ++r)
      EP[((w * 4 + dt) * 4 + r) * 64 + lane] = o[dt][r];
  __syncthreads();
  const int dtA = w & 3;
  const int r0 = (w >> 2) * 2;
  float scale[2];
  #pragma unroll
  for (int i = 0; i < 2; ++i) {
    const float4* lp = (const float4*)&EPL[(4 * g + r0 + i) * 40];
    float L = 0.f;
    #pragma unroll
    for (int k = 0; k < 8; ++k) {
      float4 v = lp[k];
      L += (v.x + v.y) + (v.z + v.w);
    }
    scale[i] = 1.0f / (L * 0.8f);
  }
  #pragma unroll
  for (int i = 0; i < 2; ++i) {
    const int rr = r0 + i;
    const int base = (dtA * 4 + rr) * 64 + lane;
    float tot = 0.f;
    #pragma unroll
    for (int w2 = 0; w2 < 8; ++w2) tot += EP[w2 * 1024 + base];
    out[((size_t)b * 2048 + m0 + 4 * g + rr) * 128 + dtA * 16 + l15] =
        tot * scale[i];
  }
  __syncthreads();
  #pragma unroll
  for (int dt = 0; dt < 4; ++dt)
    #pragma unroll
    for (int r = 0; r < 4; ++r)
      EP[((w * 4 + dt) * 4 + r) * 64 + lane] = o[dt + 4][r];
  __syncthreads();
  const int dtB = dtA + 4;
  #pragma unroll
  for (int i = 0; i < 2; ++i) {
    const int rr = r0 + i;
    const int base = (dtA * 4 + rr) * 64 + lane;
    float tot = 0.f;
    #pragma unroll
    for (int w2 = 0; w2 < 8; ++w2) tot += EP[w2 * 1024 + base];
    out[((size_t)b * 2048 + m0 + 4 * g + rr) * 128 + dtB * 16 + l15] =
        tot * scale[i];
  }
}

// ---------------------------------------------------------------------------
// Fallback 1 (R10, harness-verified 92us): inline threefry, needs 8MB ws.
// ---------------------------------------------------------------------------
__launch_bounds__(512, 4)
__global__ void attn4_kernel(const float* __restrict__ x1,
                             const uint4* __restrict__ KF,
                             const uint4* __restrict__ VF,
                             float* __restrict__ out) {
  __shared__ __attribute__((aligned(16))) uint32_t SMEM[8832];

  const int tid = threadIdx.x;
  const int w = __builtin_amdgcn_readfirstlane(tid >> 6);
  const int lane = tid & 63;
  const int l15 = lane & 15;
  const int g = lane >> 4;
  const int id = blockIdx.y * 128 + blockIdx.x;
  const int b = id & 7;
  const int mt = id >> 3;
  const int m0 = mt * 16;
  const int t0 = (mt + w) & 7;

  uint32_t* Qld = &SMEM[0];
  uint32_t* PbW = &SMEM[1024 + w * 320];

  const float QSCALE = 0.5f * 1.44269504088896340736f;
  if (w == 0) {
    const float* qp_base = x1 + ((size_t)b * 2048 + m0 + l15) * 128;
    #pragma unroll
    for (int c = 0; c < 4; ++c) {
      const float* qp = qp_base + c * 32 + g * 8;
      float4 f0 = *(const float4*)(qp);
      float4 f1 = *(const float4*)(qp + 4);
      uint4 u;
      u.x = pack_bf16(f0.x * QSCALE, f0.y * QSCALE);
      u.y = pack_bf16(f0.z * QSCALE, f0.w * QSCALE);
      u.z = pack_bf16(f1.x * QSCALE, f1.y * QSCALE);
      u.w = pack_bf16(f1.z * QSCALE, f1.w * QSCALE);
      *(uint4*)&Qld[(c * 64 + lane) * 4] = u;
    }
  }
  __syncthreads();

  f32x4 o[8];
  #pragma unroll
  for (int dt = 0; dt < 8; ++dt) o[dt] = (f32x4){0.f, 0.f, 0.f, 0.f};
  float lsum = 0.f;

  const uint32_t rbg = (uint32_t)b * 4194304u +
                       (uint32_t)(m0 + l15) * 2048u + (uint32_t)(w * 256) +
                       (uint32_t)(4 * g);

  const uint4* kfb = KF + (size_t)((b * 64 + w * 8) * 8) * 64 + lane;
  const uint4* vfb = VF + (size_t)((b * 64 + w * 8) * 8) * 64 + lane;

  for (int tile = 0; tile < 8; ++tile) {
    const int tt = (t0 + tile) & 7;
    const uint4* kfp = kfb + (size_t)tt * 512;
    const uint4* vfp = vfb + (size_t)tt * 512;

    f32x4 sa[2];
    sa[0] = (f32x4){0.f, 0.f, 0.f, 0.f};
    sa[1] = (f32x4){0.f, 0.f, 0.f, 0.f};
    __builtin_amdgcn_s_setprio(1);
    #pragma unroll
    for (int c = 0; c < 4; ++c) {
      bf16x8 qc = __builtin_bit_cast(bf16x8, *(const uint4*)&Qld[(c * 64 + lane) * 4]);
      bf16x8 k0 = __builtin_bit_cast(bf16x8, kfp[(c * 2 + 0) * 64]);
      bf16x8 k1 = __builtin_bit_cast(bf16x8, kfp[(c * 2 + 1) * 64]);
      sa[0] = __builtin_amdgcn_mfma_f32_16x16x32_bf16(k0, qc, sa[0], 0, 0, 0);
      sa[1] = __builtin_amdgcn_mfma_f32_16x16x32_bf16(k1, qc, sa[1], 0, 0, 0);
    }
    __builtin_amdgcn_s_setprio(0);

    #pragma unroll
    for (int t = 0; t < 2; ++t) {
      float p0 = __builtin_amdgcn_exp2f(sa[t][0]);
      float p1 = __builtin_amdgcn_exp2f(sa[t][1]);
      float p2 = __builtin_amdgcn_exp2f(sa[t][2]);
      float p3 = __builtin_amdgcn_exp2f(sa[t][3]);
      lsum += (p0 + p1) + (p2 + p3);
      const uint32_t ib = rbg + (uint32_t)(tt * 32 + t * 16);
      uint32_t h0, h1, bits;
      threefry2x32_k42(0u, ib + 0u, h0, h1); bits = h0 ^ h1;
      float q0 = (bits < KEEP_LT) ? p0 : 0.0f;
      threefry2x32_k42(0u, ib + 1u, h0, h1); bits = h0 ^ h1;
      float q1 = (bits < KEEP_LT) ? p1 : 0.0f;
      threefry2x32_k42(0u, ib + 2u, h0, h1); bits = h0 ^ h1;
      float q2 = (bits < KEEP_LT) ? p2 : 0.0f;
      threefry2x32_k42(0u, ib + 3u, h0, h1); bits = h0 ^ h1;
      float q3 = (bits < KEEP_LT) ? p3 : 0.0f;
      *(uint2*)&PbW[l15 * 20 + t * 8 + 2 * g] =
          make_uint2(pack_bf16(q0, q1), pack_bf16(q2, q3));
    }
    asm volatile("s_waitcnt lgkmcnt(0)" ::: "memory");
    uint4 pu = *(const uint4*)&PbW[l15 * 20 + 4 * g];
    bf16x8 pav = __builtin_bit_cast(bf16x8, pu);

    __builtin_amdgcn_s_setprio(1);
    #pragma unroll
    for (int dt = 0; dt < 8; ++dt) {
      bf16x8 vb = __builtin_bit_cast(bf16x8, vfp[dt * 64]);
      o[dt] = __builtin_amdgcn_mfma_f32_16x16x32_bf16(pav, vb, o[dt], 0, 0, 0);
    }
    __builtin_amdgcn_s_setprio(0);
  }

  __syncthreads();
  float* EP = (float*)&SMEM[0];
  float* EPL = EP + 8192;
  EPL[l15 * 40 + w * 4 + g] = lsum;
  #pragma unroll
  for (int dt = 0; dt < 4; ++dt)
    #pragma unroll
    for (int r = 0; r < 4; ++r)
      EP[((w * 4 + dt) * 4 + r) * 64 + lane] = o[dt][r];
  __syncthreads();
  const int dtA = w & 3;
  const int r0 = (w >> 2) * 2;
  float scale[2];
  #pragma unroll
  for (int i = 0; i < 2; ++i) {
    const float4* lp = (const float4*)&EPL[(4 * g + r0 + i) * 40];
    float L = 0.f;
    #pragma unroll
    for (int k = 0; k < 8; ++k) {
      float4 v = lp[k];
      L += (v.x + v.y) + (v.z + v.w);
    }
    scale[i] = 1.0f / (L * 0.8f);
  }
  #pragma unroll
  for (int i = 0; i < 2; ++i) {
    const int rr = r0 + i;
    const int base = (dtA * 4 + rr) * 64 + lane;
    float tot = 0.f;
    #pragma unroll
    for (int w2 = 0; w2 < 8; ++w2) tot += EP[w2 * 1024 + base];
    out[((size_t)b * 2048 + m0 + 4 * g + rr) * 128 + dtA * 16 + l15] =
        tot * scale[i];
  }
  __syncthreads();
  #pragma unroll
  for (int dt = 0; dt < 4; ++dt)
    #pragma unroll
    for (int r = 0; r < 4; ++r)
      EP[((w * 4 + dt) * 4 + r) * 64 + lane] = o[dt + 4][r];
  __syncthreads();
  const int dtB = dtA + 4;
  #pragma unroll
  for (int i = 0; i < 2; ++i) {
    const int rr = r0 + i;
    const int base = (dtA * 4 + rr) * 64 + lane;
    float tot = 0.f;
    #pragma unroll
    for (int w2 = 0; w2 < 8; ++w2) tot += EP[w2 * 1024 + base];
    out[((size_t)b * 2048 + m0 + 4 * g + rr) * 128 + dtB * 16 + l15] =
        tot * scale[i];
  }
}

// ---------------------------------------------------------------------------
// Fallback 2 (R4, harness-verified 107us): no workspace needed.
// ---------------------------------------------------------------------------
union FragAB {
  bf16x8 v;
  uint32_t u[4];
};

__launch_bounds__(256, 2)
__global__ void attn_kernel(const float* __restrict__ x1,
                            const float* __restrict__ x2,
                            float* __restrict__ out) {
  __shared__ __attribute__((aligned(16))) uint32_t SMEM[4][4800];

  const int tid = threadIdx.x;
  const int wv = __builtin_amdgcn_readfirstlane(tid >> 6);
  const int lane = tid & 63;
  const int l15 = lane & 15;
  const int g = lane >> 4;
  const int b = blockIdx.y;
  const int m0 = blockIdx.x * 32;

  uint32_t* KtW = &SMEM[wv][0];
  uint32_t* VtW = &SMEM[wv][2176];
  uint32_t* PbW = &SMEM[wv][4480];

  const float QSCALE = 0.5f * 1.44269504088896340736f;
  FragAB qf[2][4];
  #pragma unroll
  for (int s = 0; s < 2; ++s) {
    const float* qp_base = x1 + ((size_t)b * 2048 + m0 + s * 16 + l15) * 128;
    #pragma unroll
    for (int c = 0; c < 4; ++c) {
      const float* qp = qp_base + c * 32 + g * 8;
      float4 f0 = *(const float4*)(qp);
      float4 f1 = *(const float4*)(qp + 4);
      qf[s][c].u[0] = pack_bf16(f0.x * QSCALE, f0.y * QSCALE);
      qf[s][c].u[1] = pack_bf16(f0.z * QSCALE, f0.w * QSCALE);
      qf[s][c].u[2] = pack_bf16(f1.x * QSCALE, f1.y * QSCALE);
      qf[s][c].u[3] = pack_bf16(f1.z * QSCALE, f1.w * QSCALE);
    }
  }

  f32x4 o[2][8];
  #pragma unroll
  for (int s = 0; s < 2; ++s)
    #pragma unroll
    for (int dt = 0; dt < 8; ++dt) o[s][dt] = (f32x4){0.f, 0.f, 0.f, 0.f};
  float lsum[2] = {0.f, 0.f};

  uint32_t rb[2];
  #pragma unroll
  for (int s = 0; s < 2; ++s)
    rb[s] = (uint32_t)b * 4194304u +
            (uint32_t)(m0 + s * 16 + l15) * 2048u + (uint32_t)(wv * 512);

  const float4* x2b4 = (const float4*)(x2 + (size_t)b * 2048 * 128);
  const uint32_t permsel = (l15 & 1) ? 0x07060302u : 0x05040100u;

  for (int tile = 0; tile < 16; ++tile) {
    const int n0g = wv * 512 + tile * 32;

    #pragma unroll
    for (int i = 0; i < 16; ++i) {
      int n = 2 * i + (lane >> 5);
      int dq = lane & 31;
      float4 v = x2b4[(size_t)(n0g + n) * 32 + dq];
      uint32_t p0 = pack_bf16(v.x, v.y);
      uint32_t p1 = pack_bf16(v.z, v.w);
      *(uint2*)&KtW[n * 68 + 2 * dq] = make_uint2(p0, p1);
      VtW[dq * 36 + n] = p0;
      VtW[(dq + 32) * 36 + n] = p1;
    }
    asm volatile("s_waitcnt lgkmcnt(0)" ::: "memory");

    f32x4 sa[2][2];
    #pragma unroll
    for (int s = 0; s < 2; ++s)
      #pragma unroll
      for (int t = 0; t < 2; ++t) sa[s][t] = (f32x4){0.f, 0.f, 0.f, 0.f};
    #pragma unroll
    for (int c = 0; c < 4; ++c) {
      FragAB k0, k1;
      uint4 a0 = *(const uint4*)&KtW[l15 * 68 + c * 16 + 4 * g];
      uint4 a1 = *(const uint4*)&KtW[(16 + l15) * 68 + c * 16 + 4 * g];
      k0.u[0] = a0.x; k0.u[1] = a0.y; k0.u[2] = a0.z; k0.u[3] = a0.w;
      k1.u[0] = a1.x; k1.u[1] = a1.y; k1.u[2] = a1.z; k1.u[3] = a1.w;
      sa[0][0] = __builtin_amdgcn_mfma_f32_16x16x32_bf16(k0.v, qf[0][c].v, sa[0][0], 0, 0, 0);
      sa[0][1] = __builtin_amdgcn_mfma_f32_16x16x32_bf16(k1.v, qf[0][c].v, sa[0][1], 0, 0, 0);
      sa[1][0] = __builtin_amdgcn_mfma_f32_16x16x32_bf16(k0.v, qf[1][c].v, sa[1][0], 0, 0, 0);
      sa[1][1] = __builtin_amdgcn_mfma_f32_16x16x32_bf16(k1.v, qf[1][c].v, sa[1][1], 0, 0, 0);
    }

    FragAB pa[2];
    #pragma unroll
    for (int s = 0; s < 2; ++s) {
      #pragma unroll
      for (int t = 0; t < 2; ++t) {
        float p0 = __builtin_amdgcn_exp2f(sa[s][t][0] - MBIAS);
        float p1 = __builtin_amdgcn_exp2f(sa[s][t][1] - MBIAS);
        float p2 = __builtin_amdgcn_exp2f(sa[s][t][2] - MBIAS);
        float p3 = __builtin_amdgcn_exp2f(sa[s][t][3] - MBIAS);
        lsum[s] += (p0 + p1) + (p2 + p3);
        uint32_t ib = rb[s] + (uint32_t)(tile * 32 + t * 16 + 4 * g);
        uint32_t h0, h1, bits;
        threefry2x32_k42(0u, ib + 0u, h0, h1); bits = h0 ^ h1;
        float q0 = (bits < KEEP_LT) ? p0 : 0.0f;
        threefry2x32_k42(0u, ib + 1u, h0, h1); bits = h0 ^ h1;
        float q1 = (bits < KEEP_LT) ? p1 : 0.0f;
        threefry2x32_k42(0u, ib + 2u, h0, h1); bits = h0 ^ h1;
        float q2 = (bits < KEEP_LT) ? p2 : 0.0f;
        threefry2x32_k42(0u, ib + 3u, h0, h1); bits = h0 ^ h1;
        float q3 = (bits < KEEP_LT) ? p3 : 0.0f;
        *(uint2*)&PbW[l15 * 20 + t * 8 + 2 * g] =
            make_uint2(pack_bf16(q0, q1), pack_bf16(q2, q3));
      }
      asm volatile("s_waitcnt lgkmcnt(0)" ::: "memory");
      uint4 pu = *(const uint4*)&PbW[l15 * 20 + 4 * g];
      pa[s].u[0] = pu.x; pa[s].u[1] = pu.y; pa[s].u[2] = pu.z; pa[s].u[3] = pu.w;
    }

    #pragma unroll
    for (int dt = 0; dt < 8; ++dt) {
      int rowp = ((l15 >> 1) & 1) * 32 + 4 * dt + (l15 >> 2);
      const uint32_t* vr = &VtW[rowp * 36 + 8 * g];
      uint4 U0 = *(const uint4*)vr;
      uint4 U1 = *(const uint4*)(vr + 4);
      FragAB vb;
      vb.u[0] = __builtin_amdgcn_perm(U0.y, U0.x, permsel);
      vb.u[1] = __builtin_amdgcn_perm(U0.w, U0.z, permsel);
      vb.u[2] = __builtin_amdgcn_perm(U1.y, U1.x, permsel);
      vb.u[3] = __builtin_amdgcn_perm(U1.w, U1.z, permsel);
      o[0][dt] = __builtin_amdgcn_mfma_f32_16x16x32_bf16(pa[0].v, vb.v, o[0][dt], 0, 0, 0);
      o[1][dt] = __builtin_amdgcn_mfma_f32_16x16x32_bf16(pa[1].v, vb.v, o[1][dt], 0, 0, 0);
    }
  }

  __syncthreads();
  float* EP = (float*)&SMEM[0][0];
  #pragma unroll
  for (int s = 0; s < 2; ++s) {
    #pragma unroll
    for (int dt = 0; dt < 8; ++dt)
      #pragma unroll
      for (int r = 0; r < 4; ++r)
        EP[(((wv * 2 + s) * 8 + dt) * 4 + r) * 64 + lane] = o[s][dt][r];
    EP[16384 + (s * 16 + l15) * 16 + wv * 4 + g] = lsum[s];
  }
  __syncthreads();
  const int s = wv >> 1;
  float scale[4];
  #pragma unroll
  for (int r = 0; r < 4; ++r) {
    const float4* lp = (const float4*)&EP[16384 + (s * 16 + 4 * g + r) * 16];
    float4 A = lp[0], B4 = lp[1], C4 = lp[2], D4 = lp[3];
    float L = ((A.x + A.y) + (A.z + A.w)) + ((B4.x + B4.y) + (B4.z + B4.w)) +
              ((C4.x + C4.y) + (C4.z + C4.w)) + ((D4.x + D4.y) + (D4.z + D4.w));
    scale[r] = 1.0f / (L * 0.8f);
  }
  #pragma unroll
  for (int it = 0; it < 4; ++it) {
    int dt = (wv * 4 + it) & 7;
    #pragma unroll
    for (int r = 0; r < 4; ++r) {
      int base = ((s * 8 + dt) * 4 + r) * 64 + lane;
      float tot = EP[base] + EP[base + 4096] + EP[base + 8192] + EP[base + 12288];
      out[((size_t)b * 2048 + m0 + s * 16 + 4 * g + r) * 128 + dt * 16 + l15] =
          tot * scale[r];
    }
  }
}

extern "C" void kernel_launch(void* const* d_in, const int* in_sizes, int n_in,
                              void* d_out, int out_size, void* d_ws, size_t ws_size,
                              hipStream_t stream) {
  const float* x1 = (const float*)d_in[0];
  const float* x2 = (const float*)d_in[1];
  float* out = (float*)d_out;
  if (d_ws != nullptr && ws_size >= (size_t)12 * 1024 * 1024) {
    uint4* KF = (uint4*)d_ws;
    uint4* VF = KF + 262144;                     // +4MB
    uint32_t* MW = (uint32_t*)(VF + 262144);     // +4MB (mask bits, 4MB)
    prep_kernel<<<dim3(64, 8, 1), dim3(256, 1, 1), 0, stream>>>(x2, KF, VF);
    maskgen_kernel<<<dim3(2048, 1, 1), dim3(256, 1, 1), 0, stream>>>(MW);
    attn5_kernel<<<dim3(128, 8, 1), dim3(512, 1, 1), 0, stream>>>(x1, KF, VF, MW, out);
  } else if (d_ws != nullptr && ws_size >= (size_t)8 * 1024 * 1024) {
    uint4* KF = (uint4*)d_ws;
    uint4* VF = KF + 262144;   // +4MB
    prep_kernel<<<dim3(64, 8, 1), dim3(256, 1, 1), 0, stream>>>(x2, KF, VF);
    attn4_kernel<<<dim3(128, 8, 1), dim3(512, 1, 1), 0, stream>>>(x1, KF, VF, out);
  } else {
    attn_kernel<<<dim3(64, 8, 1), dim3(256, 1, 1), 0, stream>>>(x1, x2, out);
  }
}

// Round 9
// 174.629 us; speedup vs baseline: 1.1181x; 1.1181x over previous
//
#include <hip/hip_runtime.h>
#include <stdint.h>

// ---------------------------------------------------------------------------
// Fused attention: out = dropout(softmax(0.5 * x1 @ x2^T), p=0.2, jax key 42) @ x2
// B=8, M=N=2048, D=128, fp32 in/out. bf16 MFMA (16x16x32), bitwise JAX threefry
// (partitionable form: bits = h0^h1 of threefry((0,42),(0,flat_idx))).
//
// R13 = R12 resubmitted (R8 bench failed at the infrastructure level:
// "MI355X container failed twice"; no counters returned. Kernel audited:
// uniform barriers, safe LDS aliasing, proven launch shapes -> resubmit).
//
// R12: fragment-stream sharing. Evidence chain:
//  - R11 split: maskgen alone ~90us; attn5 (no threefry) ~= attn4 (threefry
//    inline, 92us) -> threefry is FREE in the fused kernel; K/V L2 latency
//    dominates. Split reverted.
//  - Why latency-bound: 32 waves/CU each stream DISTINCT 16KB fragment tiles
//    -> 128KB/tile-phase through 32KB L1 -> every load L2-misses (~300cy),
//    miss queue saturates, waves convoy at load-issue (explains all the
//    prefetch/stagger/occupancy nulls of R6-R10).
// -> attn6: 512-thr block = 2 m-halves (hs) x 4 n-quarters (q). The two
//    waves of an s-pair read the IDENTICAL kf/vf tile sequence; a per-tile
//    __syncthreads keeps the block tile-aligned so each tile is fetched once
//    and shared via L1/miss-merge (2x guaranteed intra-block; co-resident
//    blocks share b for opportunistic extra merging). No stagger (alignment
//    IS the mechanism). Threefry inline. Epilogue: two m-half passes of the
//    proven 4-quarter merge. LDS 35328B. launch_bounds(512,4), VGPR<=64.
// Fallback: R4 attn (107us) if ws < 8MB.
// ---------------------------------------------------------------------------

typedef __bf16 bf16x8 __attribute__((ext_vector_type(8)));
typedef float f32x4 __attribute__((ext_vector_type(4)));

__device__ __forceinline__ uint32_t rotl32(uint32_t x, uint32_t r) {
  return (x << r) | (x >> (32u - r));   // -> v_alignbit_b32
}

// JAX threefry2x32 with key (0, 42)
__device__ __forceinline__ void threefry2x32_k42(uint32_t in0, uint32_t in1,
                                                 uint32_t& o0, uint32_t& o1) {
  const uint32_t ks0 = 0u;
  const uint32_t ks1 = 42u;
  const uint32_t ks2 = 0x1BD11BDAu ^ 0u ^ 42u;
  uint32_t x0 = in0 + ks0;
  uint32_t x1 = in1 + ks1;
#define TFR(r) { x0 += x1; x1 = rotl32(x1, r); x1 ^= x0; }
  TFR(13u) TFR(15u) TFR(26u) TFR(6u)
  x0 += ks1; x1 += ks2 + 1u;
  TFR(17u) TFR(29u) TFR(16u) TFR(24u)
  x0 += ks2; x1 += ks0 + 2u;
  TFR(13u) TFR(15u) TFR(26u) TFR(6u)
  x0 += ks0; x1 += ks1 + 3u;
  TFR(17u) TFR(29u) TFR(16u) TFR(24u)
  x0 += ks1; x1 += ks2 + 4u;
  TFR(13u) TFR(15u) TFR(26u) TFR(6u)
  x0 += ks2; x1 += ks0 + 5u;
#undef TFR
  o0 = x0; o1 = x1;
}

__device__ __forceinline__ uint32_t pack_bf16(float a, float b) {
  __bf16 ba = (__bf16)a;   // RTNE
  __bf16 bb = (__bf16)b;
  uint32_t ua = (uint32_t)__builtin_bit_cast(uint16_t, ba);
  uint32_t ub = (uint32_t)__builtin_bit_cast(uint16_t, bb);
  return ua | (ub << 16);
}

// keep iff uniform < 0.8f  <=>  bits < 6710887<<9
#define KEEP_LT 3435974144u
#define MBIAS 40.0f   // used only by the R4 fallback kernel

// ---------------------------------------------------------------------------
// Prepass: pack x2 (f32) into fragment-ordered bf16 layouts in workspace.
//   KF[((b*64+T)*8 + c*2+h)*64 + lane] (uint4):
//     A-frag for QK^T: rows n = T*32 + h*16 + l15, 8 bf16 at d = c*32+8g..+7
//   VF[((b*64+T)*8 + dt)*64 + lane] (uint4):
//     B-frag for PV: u[j] = pack(x2[T*32+8g+2j][dt*16+l15], x2[..+2j+1][..])
// Each 4MB, total 8MB.
// ---------------------------------------------------------------------------
__launch_bounds__(256, 4)
__global__ void prep_kernel(const float* __restrict__ x2,
                            uint4* __restrict__ KF,
                            uint4* __restrict__ VF) {
  const int tid = threadIdx.x;
  const int w = tid >> 6;        // 0..3  (= c for KF; = dt base for VF)
  const int lane = tid & 63;
  const int l15 = lane & 15;
  const int g = lane >> 4;
  const int T = blockIdx.x;      // 0..63 (32-row n-tile)
  const int b = blockIdx.y;
  const float* xb = x2 + (size_t)b * 2048 * 128;

  #pragma unroll
  for (int h = 0; h < 2; ++h) {
    const int n = T * 32 + h * 16 + l15;
    const float* p = xb + (size_t)n * 128 + w * 32 + 8 * g;
    float4 f0 = *(const float4*)(p);
    float4 f1 = *(const float4*)(p + 4);
    uint4 u;
    u.x = pack_bf16(f0.x, f0.y);
    u.y = pack_bf16(f0.z, f0.w);
    u.z = pack_bf16(f1.x, f1.y);
    u.w = pack_bf16(f1.z, f1.w);
    KF[(size_t)((b * 64 + T) * 8 + w * 2 + h) * 64 + lane] = u;
  }

  #pragma unroll
  for (int i = 0; i < 2; ++i) {
    const int dt = w + 4 * i;
    const int d = dt * 16 + l15;
    const float* p = xb + (size_t)(T * 32 + 8 * g) * 128 + d;
    uint4 u;
    u.x = pack_bf16(p[0],   p[128]);
    u.y = pack_bf16(p[256], p[384]);
    u.z = pack_bf16(p[512], p[640]);
    u.w = pack_bf16(p[768], p[896]);
    VF[(size_t)((b * 64 + T) * 8 + dt) * 64 + lane] = u;
  }
}

// ---------------------------------------------------------------------------
// Main kernel: 32 m-rows per block; 8 waves = 2 m-halves x 4 n-quarters.
// The two waves of each (q) pair consume IDENTICAL kf/vf tile streams,
// kept tile-aligned by a per-tile barrier -> each fragment tile is fetched
// once from L2 and shared (L1 hit / miss-merge) by its pair.
// ---------------------------------------------------------------------------
__launch_bounds__(512, 4)
__global__ void attn6_kernel(const float* __restrict__ x1,
                             const uint4* __restrict__ KF,
                             const uint4* __restrict__ VF,
                             float* __restrict__ out) {
  // LDS 8832 words = 35328B.
  // Main loop:  Qld [0..2048): 2 halves x shared Q-frags (c*64+lane);
  //             Pb  [2048..4608): 8 waves x 320 words (wave-private).
  // Epilogue (aliases all): EP 8192 f + EPL 576 f (one m-half per pass).
  __shared__ __attribute__((aligned(16))) uint32_t SMEM[8832];

  const int tid = threadIdx.x;
  const int w = __builtin_amdgcn_readfirstlane(tid >> 6);   // 0..7
  const int lane = tid & 63;
  const int l15 = lane & 15;
  const int g = lane >> 4;
  const int q = w & 3;          // n-quarter (512 cols, 16 tiles)
  const int hs = w >> 2;        // m-half (16 rows)
  // XCD batch swizzle: b = id&7 -> one batch per XCD (L2-resident slices).
  const int id = blockIdx.y * 64 + blockIdx.x;
  const int b = id & 7;
  const int mt = id >> 3;       // 0..63
  const int m0 = mt * 32;

  uint32_t* Qld = &SMEM[0];
  uint32_t* PbW = &SMEM[2048 + w * 320];

  // ---- stage Q fragments to LDS once (waves 0 and 4 stage their halves) ----
  const float QSCALE = 0.5f * 1.44269504088896340736f;
  if (q == 0) {
    const float* qp_base =
        x1 + ((size_t)b * 2048 + m0 + hs * 16 + l15) * 128;
    #pragma unroll
    for (int c = 0; c < 4; ++c) {
      const float* qp = qp_base + c * 32 + g * 8;
      float4 f0 = *(const float4*)(qp);
      float4 f1 = *(const float4*)(qp + 4);
      uint4 u;
      u.x = pack_bf16(f0.x * QSCALE, f0.y * QSCALE);
      u.y = pack_bf16(f0.z * QSCALE, f0.w * QSCALE);
      u.z = pack_bf16(f1.x * QSCALE, f1.y * QSCALE);
      u.w = pack_bf16(f1.z * QSCALE, f1.w * QSCALE);
      *(uint4*)&Qld[hs * 1024 + (c * 64 + lane) * 4] = u;
    }
  }
  __syncthreads();

  f32x4 o[8];
  #pragma unroll
  for (int dt = 0; dt < 8; ++dt) o[dt] = (f32x4){0.f, 0.f, 0.f, 0.f};
  float lsum = 0.f;

  // RNG row base with per-lane 4g folded in: element (tile,t,r) has
  // in1 = rbg + tile*32 + t*16 + r.
  const uint32_t rbg = (uint32_t)b * 4194304u +
                       (uint32_t)(m0 + hs * 16 + l15) * 2048u +
                       (uint32_t)(q * 512) + (uint32_t)(4 * g);

  const uint4* kfp = KF + (size_t)((b * 64 + q * 16) * 8) * 64 + lane;
  const uint4* vfp = VF + (size_t)((b * 64 + q * 16) * 8) * 64 + lane;

  for (int tile = 0; tile < 16; ++tile) {
    // ---- S^T = K Q^T : C/D row = n (4g+r), col = m (l15). The s-pair
    // twin wave issues the SAME kf addresses this tile (shared fetch). ----
    f32x4 sa[2];
    sa[0] = (f32x4){0.f, 0.f, 0.f, 0.f};
    sa[1] = (f32x4){0.f, 0.f, 0.f, 0.f};
    __builtin_amdgcn_s_setprio(1);
    #pragma unroll
    for (int c = 0; c < 4; ++c) {
      bf16x8 qc = __builtin_bit_cast(
          bf16x8, *(const uint4*)&Qld[hs * 1024 + (c * 64 + lane) * 4]);
      bf16x8 k0 = __builtin_bit_cast(bf16x8, kfp[(c * 2 + 0) * 64]);
      bf16x8 k1 = __builtin_bit_cast(bf16x8, kfp[(c * 2 + 1) * 64]);
      sa[0] = __builtin_amdgcn_mfma_f32_16x16x32_bf16(k0, qc, sa[0], 0, 0, 0);
      sa[1] = __builtin_amdgcn_mfma_f32_16x16x32_bf16(k1, qc, sa[1], 0, 0, 0);
    }
    __builtin_amdgcn_s_setprio(0);

    // ---- softmax (unbiased exp2; uniform 2^bias cancels in L-normalize) +
    //      inline bitwise dropout (threefry rides the stall windows) ----
    #pragma unroll
    for (int t = 0; t < 2; ++t) {
      float p0 = __builtin_amdgcn_exp2f(sa[t][0]);
      float p1 = __builtin_amdgcn_exp2f(sa[t][1]);
      float p2 = __builtin_amdgcn_exp2f(sa[t][2]);
      float p3 = __builtin_amdgcn_exp2f(sa[t][3]);
      lsum += (p0 + p1) + (p2 + p3);   // denominator uses UNMASKED probs
      const uint32_t ib = rbg + (uint32_t)(tile * 32 + t * 16);
      uint32_t h0, h1, bits;
      threefry2x32_k42(0u, ib + 0u, h0, h1); bits = h0 ^ h1;
      float q0 = (bits < KEEP_LT) ? p0 : 0.0f;
      threefry2x32_k42(0u, ib + 1u, h0, h1); bits = h0 ^ h1;
      float q1 = (bits < KEEP_LT) ? p1 : 0.0f;
      threefry2x32_k42(0u, ib + 2u, h0, h1); bits = h0 ^ h1;
      float q2 = (bits < KEEP_LT) ? p2 : 0.0f;
      threefry2x32_k42(0u, ib + 3u, h0, h1); bits = h0 ^ h1;
      float q3 = (bits < KEEP_LT) ? p3 : 0.0f;
      *(uint2*)&PbW[l15 * 20 + t * 8 + 2 * g] =
          make_uint2(pack_bf16(q0, q1), pack_bf16(q2, q3));
    }
    asm volatile("s_waitcnt lgkmcnt(0)" ::: "memory");  // in-order DS per wave
    uint4 pu = *(const uint4*)&PbW[l15 * 20 + 4 * g];   // A-frag: m=l15, k=8g+j
    bf16x8 pav = __builtin_bit_cast(bf16x8, pu);

    // ---- O += P V : vf addresses also shared with the twin wave ----
    __builtin_amdgcn_s_setprio(1);
    #pragma unroll
    for (int dt = 0; dt < 8; ++dt) {
      bf16x8 vb = __builtin_bit_cast(bf16x8, vfp[dt * 64]);
      o[dt] = __builtin_amdgcn_mfma_f32_16x16x32_bf16(pav, vb, o[dt], 0, 0, 0);
    }
    __builtin_amdgcn_s_setprio(0);

    kfp += 512;
    vfp += 512;
    // Keep all 8 waves tile-aligned: the sharing mechanism. Also desyncs
    // nothing we need (no stagger by design).
    __syncthreads();
  }

  // ---- epilogue: two m-half passes; each merges the 4 n-quarters ----
  float* EP = (float*)&SMEM[0];
  float* EPL = EP + 8192;
  #pragma unroll
  for (int pass = 0; pass < 2; ++pass) {
    if (pass == 1) __syncthreads();   // first pass already fenced by loop tail
    if (hs == pass) {
      // L partials: row m (16) x (q*4+g), stride 36 (conflict-free). 256 f.
      EPL[l15 * 36 + q * 4 + g] = lsum;
      // O partials: [(q*8+dt)*4+r] x lane. 8192 f.
      #pragma unroll
      for (int dt = 0; dt < 8; ++dt)
        #pragma unroll
        for (int r = 0; r < 4; ++r)
          EP[((q * 8 + dt) * 4 + r) * 64 + lane] = o[dt][r];
    }
    __syncthreads();
    // All 8 waves reduce: wave w handles dt = w for this pass's 16 rows.
    float scale[4];
    #pragma unroll
    for (int r = 0; r < 4; ++r) {
      const float4* lp = (const float4*)&EPL[(4 * g + r) * 36];
      float4 A = lp[0], B4 = lp[1], C4 = lp[2], D4 = lp[3];
      float L = ((A.x + A.y) + (A.z + A.w)) + ((B4.x + B4.y) + (B4.z + B4.w)) +
                ((C4.x + C4.y) + (C4.z + C4.w)) + ((D4.x + D4.y) + (D4.z + D4.w));
      scale[r] = 1.0f / (L * 0.8f);
    }
    #pragma unroll
    for (int r = 0; r < 4; ++r) {
      const int base = (w * 4 + r) * 64 + lane;
      float tot = EP[base] + EP[base + 2048] + EP[base + 4096] + EP[base + 6144];
      out[((size_t)b * 2048 + m0 + pass * 16 + 4 * g + r) * 128 + w * 16 + l15] =
          tot * scale[r];
    }
  }
}

// ---------------------------------------------------------------------------
// Fallback (R4, harness-verified 107us): used only if workspace < 8MB.
// ---------------------------------------------------------------------------
union FragAB {
  bf16x8 v;
  uint32_t u[4];
};

__launch_bounds__(256, 2)
__global__ void attn_kernel(const float* __restrict__ x1,
                            const float* __restrict__ x2,
                            float* __restrict__ out) {
  __shared__ __attribute__((aligned(16))) uint32_t SMEM[4][4800];

  const int tid = threadIdx.x;
  const int wv = __builtin_amdgcn_readfirstlane(tid >> 6);
  const int lane = tid & 63;
  const int l15 = lane & 15;
  const int g = lane >> 4;
  const int b = blockIdx.y;
  const int m0 = blockIdx.x * 32;

  uint32_t* KtW = &SMEM[wv][0];
  uint32_t* VtW = &SMEM[wv][2176];
  uint32_t* PbW = &SMEM[wv][4480];

  const float QSCALE = 0.5f * 1.44269504088896340736f;
  FragAB qf[2][4];
  #pragma unroll
  for (int s = 0; s < 2; ++s) {
    const float* qp_base = x1 + ((size_t)b * 2048 + m0 + s * 16 + l15) * 128;
    #pragma unroll
    for (int c = 0; c < 4; ++c) {
      const float* qp = qp_base + c * 32 + g * 8;
      float4 f0 = *(const float4*)(qp);
      float4 f1 = *(const float4*)(qp + 4);
      qf[s][c].u[0] = pack_bf16(f0.x * QSCALE, f0.y * QSCALE);
      qf[s][c].u[1] = pack_bf16(f0.z * QSCALE, f0.w * QSCALE);
      qf[s][c].u[2] = pack_bf16(f1.x * QSCALE, f1.y * QSCALE);
      qf[s][c].u[3] = pack_bf16(f1.z * QSCALE, f1.w * QSCALE);
    }
  }

  f32x4 o[2][8];
  #pragma unroll
  for (int s = 0; s < 2; ++s)
    #pragma unroll
    for (int dt = 0; dt < 8; ++dt) o[s][dt] = (f32x4){0.f, 0.f, 0.f, 0.f};
  float lsum[2] = {0.f, 0.f};

  uint32_t rb[2];
  #pragma unroll
  for (int s = 0; s < 2; ++s)
    rb[s] = (uint32_t)b * 4194304u +
            (uint32_t)(m0 + s * 16 + l15) * 2048u + (uint32_t)(wv * 512);

  const float4* x2b4 = (const float4*)(x2 + (size_t)b * 2048 * 128);
  const uint32_t permsel = (l15 & 1) ? 0x07060302u : 0x05040100u;

  for (int tile = 0; tile < 16; ++tile) {
    const int n0g = wv * 512 + tile * 32;

    #pragma unroll
    for (int i = 0; i < 16; ++i) {
      int n = 2 * i + (lane >> 5);
      int dq = lane & 31;
      float4 v = x2b4[(size_t)(n0g + n) * 32 + dq];
      uint32_t p0 = pack_bf16(v.x, v.y);
      uint32_t p1 = pack_bf16(v.z, v.w);
      *(uint2*)&KtW[n * 68 + 2 * dq] = make_uint2(p0, p1);
      VtW[dq * 36 + n] = p0;
      VtW[(dq + 32) * 36 + n] = p1;
    }
    asm volatile("s_waitcnt lgkmcnt(0)" ::: "memory");

    f32x4 sa[2][2];
    #pragma unroll
    for (int s = 0; s < 2; ++s)
      #pragma unroll
      for (int t = 0; t < 2; ++t) sa[s][t] = (f32x4){0.f, 0.f, 0.f, 0.f};
    #pragma unroll
    for (int c = 0; c < 4; ++c) {
      FragAB k0, k1;
      uint4 a0 = *(const uint4*)&KtW[l15 * 68 + c * 16 + 4 * g];
      uint4 a1 = *(const uint4*)&KtW[(16 + l15) * 68 + c * 16 + 4 * g];
      k0.u[0] = a0.x; k0.u[1] = a0.y; k0.u[2] = a0.z; k0.u[3] = a0.w;
      k1.u[0] = a1.x; k1.u[1] = a1.y; k1.u[2] = a1.z; k1.u[3] = a1.w;
      sa[0][0] = __builtin_amdgcn_mfma_f32_16x16x32_bf16(k0.v, qf[0][c].v, sa[0][0], 0, 0, 0);
      sa[0][1] = __builtin_amdgcn_mfma_f32_16x16x32_bf16(k1.v, qf[0][c].v, sa[0][1], 0, 0, 0);
      sa[1][0] = __builtin_amdgcn_mfma_f32_16x16x32_bf16(k0.v, qf[1][c].v, sa[1][0], 0, 0, 0);
      sa[1][1] = __builtin_amdgcn_mfma_f32_16x16x32_bf16(k1.v, qf[1][c].v, sa[1][1], 0, 0, 0);
    }

    FragAB pa[2];
    #pragma unroll
    for (int s = 0; s < 2; ++s) {
      #pragma unroll
      for (int t = 0; t < 2; ++t) {
        float p0 = __builtin_amdgcn_exp2f(sa[s][t][0] - MBIAS);
        float p1 = __builtin_amdgcn_exp2f(sa[s][t][1] - MBIAS);
        float p2 = __builtin_amdgcn_exp2f(sa[s][t][2] - MBIAS);
        float p3 = __builtin_amdgcn_exp2f(sa[s][t][3] - MBIAS);
        lsum[s] += (p0 + p1) + (p2 + p3);
        uint32_t ib = rb[s] + (uint32_t)(tile * 32 + t * 16 + 4 * g);
        uint32_t h0, h1, bits;
        threefry2x32_k42(0u, ib + 0u, h0, h1); bits = h0 ^ h1;
        float q0 = (bits < KEEP_LT) ? p0 : 0.0f;
        threefry2x32_k42(0u, ib + 1u, h0, h1); bits = h0 ^ h1;
        float q1 = (bits < KEEP_LT) ? p1 : 0.0f;
        threefry2x32_k42(0u, ib + 2u, h0, h1); bits = h0 ^ h1;
        float q2 = (bits < KEEP_LT) ? p2 : 0.0f;
        threefry2x32_k42(0u, ib + 3u, h0, h1); bits = h0 ^ h1;
        float q3 = (bits < KEEP_LT) ? p3 : 0.0f;
        *(uint2*)&PbW[l15 * 20 + t * 8 + 2 * g] =
            make_uint2(pack_bf16(q0, q1), pack_bf16(q2, q3));
      }
      asm volatile("s_waitcnt lgkmcnt(0)" ::: "memory");
      uint4 pu = *(const uint4*)&PbW[l15 * 20 + 4 * g];
      pa[s].u[0] = pu.x; pa[s].u[1] = pu.y; pa[s].u[2] = pu.z; pa[s].u[3] = pu.w;
    }

    #pragma unroll
    for (int dt = 0; dt < 8; ++dt) {
      int rowp = ((l15 >> 1) & 1) * 32 + 4 * dt + (l15 >> 2);
      const uint32_t* vr = &VtW[rowp * 36 + 8 * g];
      uint4 U0 = *(const uint4*)vr;
      uint4 U1 = *(const uint4*)(vr + 4);
      FragAB vb;
      vb.u[0] = __builtin_amdgcn_perm(U0.y, U0.x, permsel);
      vb.u[1] = __builtin_amdgcn_perm(U0.w, U0.z, permsel);
      vb.u[2] = __builtin_amdgcn_perm(U1.y, U1.x, permsel);
      vb.u[3] = __builtin_amdgcn_perm(U1.w, U1.z, permsel);
      o[0][dt] = __builtin_amdgcn_mfma_f32_16x16x32_bf16(pa[0].v, vb.v, o[0][dt], 0, 0, 0);
      o[1][dt] = __builtin_amdgcn_mfma_f32_16x16x32_bf16(pa[1].v, vb.v, o[1][dt], 0, 0, 0);
    }
  }

  __syncthreads();
  float* EP = (float*)&SMEM[0][0];
  #pragma unroll
  for (int s = 0; s < 2; ++s) {
    #pragma unroll
    for (int dt = 0; dt < 8; ++dt)
      #pragma unroll
      for (int r = 0; r < 4; ++r)
        EP[(((wv * 2 + s) * 8 + dt) * 4 + r) * 64 + lane] = o[s][dt][r];
    EP[16384 + (s * 16 + l15) * 16 + wv * 4 + g] = lsum[s];
  }
  __syncthreads();
  const int s = wv >> 1;
  float scale[4];
  #pragma unroll
  for (int r = 0; r < 4; ++r) {
    const float4* lp = (const float4*)&EP[16384 + (s * 16 + 4 * g + r) * 16];
    float4 A = lp[0], B4 = lp[1], C4 = lp[2], D4 = lp[3];
    float L = ((A.x + A.y) + (A.z + A.w)) + ((B4.x + B4.y) + (B4.z + B4.w)) +
              ((C4.x + C4.y) + (C4.z + C4.w)) + ((D4.x + D4.y) + (D4.z + D4.w));
    scale[r] = 1.0f / (L * 0.8f);
  }
  #pragma unroll
  for (int it = 0; it < 4; ++it) {
    int dt = (wv * 4 + it) & 7;
    #pragma unroll
    for (int r = 0; r < 4; ++r) {
      int base = ((s * 8 + dt) * 4 + r) * 64 + lane;
      float tot = EP[base] + EP[base + 4096] + EP[base + 8192] + EP[base + 12288];
      out[((size_t)b * 2048 + m0 + s * 16 + 4 * g + r) * 128 + dt * 16 + l15] =
          tot * scale[r];
    }
  }
}

extern "C" void kernel_launch(void* const* d_in, const int* in_sizes, int n_in,
                              void* d_out, int out_size, void* d_ws, size_t ws_size,
                              hipStream_t stream) {
  const float* x1 = (const float*)d_in[0];
  const float* x2 = (const float*)d_in[1];
  float* out = (float*)d_out;
  if (d_ws != nullptr && ws_size >= (size_t)8 * 1024 * 1024) {
    uint4* KF = (uint4*)d_ws;
    uint4* VF = KF + 262144;   // +4MB
    prep_kernel<<<dim3(64, 8, 1), dim3(256, 1, 1), 0, stream>>>(x2, KF, VF);
    attn6_kernel<<<dim3(64, 8, 1), dim3(512, 1, 1), 0, stream>>>(x1, KF, VF, out);
  } else {
    attn_kernel<<<dim3(64, 8, 1), dim3(256, 1, 1), 0, stream>>>(x1, x2, out);
  }
}

// Round 10
// 152.973 us; speedup vs baseline: 1.2764x; 1.1416x over previous
//
#include <hip/hip_runtime.h>
#include <stdint.h>

// ---------------------------------------------------------------------------
// Fused attention: out = dropout(softmax(0.5 * x1 @ x2^T), p=0.2, jax key 42) @ x2
// B=8, M=N=2048, D=128, fp32 in/out. bf16 MFMA (16x16x32), bitwise JAX threefry
// (partitionable form: bits = h0^h1 of threefry((0,42),(0,flat_idx))).
//
// R14: intra-wave fragment reuse (2 m-slabs/wave). Evidence chain:
//  - R11: attn5 (threefry deleted) ~= attn4 (inline, 92us) -> VALU volume is
//    NOT the limiter; VALUBusy is a misleading proxy here.
//  - All ~90us variants fetch each KF/VF uint4 from L2 once per wave ->
//    1.02GB L2->CU, ~21 Greq/s/XCD: at the L2 REQUEST-RATE ceiling while
//    byte-BW is ~1/3 of peak. The time scales with redundant requests.
//  - R12/R13 (cross-wave sharing via barrier alignment): 120us, falsified —
//    no HW miss-merge across waves, barrier aligns stalls.
// -> attn7 = R9's proven pipeline (90.5us) widened to 32 m-rows per wave:
//    one kf/vf load now feeds TWO m-slabs (sharing by construction, in-wave).
//    Global requests per unit work halve (1.02GB -> 524MB). Grid 512 blocks
//    (64 m-blocks x 8 b) x 4 waves; launch_bounds(256,2) -> VGPR cap 256
//    (o[2][8]+qf[2][4] ~ 170 used, no spill). Keeps: XCD b-swizzle, tile
//    stagger, setprio, inline threefry, unbiased exp2, proven epilogue
//    (two slab passes). LDS 35328B; Pb 640 words/wave, one fence per tile.
// Fallback: R4 attn (107us) if ws < 8MB.
// ---------------------------------------------------------------------------

typedef __bf16 bf16x8 __attribute__((ext_vector_type(8)));
typedef float f32x4 __attribute__((ext_vector_type(4)));

__device__ __forceinline__ uint32_t rotl32(uint32_t x, uint32_t r) {
  return (x << r) | (x >> (32u - r));   // -> v_alignbit_b32
}

// JAX threefry2x32 with key (0, 42)
__device__ __forceinline__ void threefry2x32_k42(uint32_t in0, uint32_t in1,
                                                 uint32_t& o0, uint32_t& o1) {
  const uint32_t ks0 = 0u;
  const uint32_t ks1 = 42u;
  const uint32_t ks2 = 0x1BD11BDAu ^ 0u ^ 42u;
  uint32_t x0 = in0 + ks0;
  uint32_t x1 = in1 + ks1;
#define TFR(r) { x0 += x1; x1 = rotl32(x1, r); x1 ^= x0; }
  TFR(13u) TFR(15u) TFR(26u) TFR(6u)
  x0 += ks1; x1 += ks2 + 1u;
  TFR(17u) TFR(29u) TFR(16u) TFR(24u)
  x0 += ks2; x1 += ks0 + 2u;
  TFR(13u) TFR(15u) TFR(26u) TFR(6u)
  x0 += ks0; x1 += ks1 + 3u;
  TFR(17u) TFR(29u) TFR(16u) TFR(24u)
  x0 += ks1; x1 += ks2 + 4u;
  TFR(13u) TFR(15u) TFR(26u) TFR(6u)
  x0 += ks2; x1 += ks0 + 5u;
#undef TFR
  o0 = x0; o1 = x1;
}

__device__ __forceinline__ uint32_t pack_bf16(float a, float b) {
  __bf16 ba = (__bf16)a;   // RTNE
  __bf16 bb = (__bf16)b;
  uint32_t ua = (uint32_t)__builtin_bit_cast(uint16_t, ba);
  uint32_t ub = (uint32_t)__builtin_bit_cast(uint16_t, bb);
  return ua | (ub << 16);
}

// keep iff uniform < 0.8f  <=>  bits < 6710887<<9
#define KEEP_LT 3435974144u
#define MBIAS 40.0f   // used only by the R4 fallback kernel

// ---------------------------------------------------------------------------
// Prepass: pack x2 (f32) into fragment-ordered bf16 layouts in workspace.
//   KF[((b*64+T)*8 + c*2+h)*64 + lane] (uint4):
//     A-frag for QK^T: rows n = T*32 + h*16 + l15, 8 bf16 at d = c*32+8g..+7
//   VF[((b*64+T)*8 + dt)*64 + lane] (uint4):
//     B-frag for PV: u[j] = pack(x2[T*32+8g+2j][dt*16+l15], x2[..+2j+1][..])
// Each 4MB, total 8MB.
// ---------------------------------------------------------------------------
__launch_bounds__(256, 4)
__global__ void prep_kernel(const float* __restrict__ x2,
                            uint4* __restrict__ KF,
                            uint4* __restrict__ VF) {
  const int tid = threadIdx.x;
  const int w = tid >> 6;        // 0..3  (= c for KF; = dt base for VF)
  const int lane = tid & 63;
  const int l15 = lane & 15;
  const int g = lane >> 4;
  const int T = blockIdx.x;      // 0..63 (32-row n-tile)
  const int b = blockIdx.y;
  const float* xb = x2 + (size_t)b * 2048 * 128;

  #pragma unroll
  for (int h = 0; h < 2; ++h) {
    const int n = T * 32 + h * 16 + l15;
    const float* p = xb + (size_t)n * 128 + w * 32 + 8 * g;
    float4 f0 = *(const float4*)(p);
    float4 f1 = *(const float4*)(p + 4);
    uint4 u;
    u.x = pack_bf16(f0.x, f0.y);
    u.y = pack_bf16(f0.z, f0.w);
    u.z = pack_bf16(f1.x, f1.y);
    u.w = pack_bf16(f1.z, f1.w);
    KF[(size_t)((b * 64 + T) * 8 + w * 2 + h) * 64 + lane] = u;
  }

  #pragma unroll
  for (int i = 0; i < 2; ++i) {
    const int dt = w + 4 * i;
    const int d = dt * 16 + l15;
    const float* p = xb + (size_t)(T * 32 + 8 * g) * 128 + d;
    uint4 u;
    u.x = pack_bf16(p[0],   p[128]);
    u.y = pack_bf16(p[256], p[384]);
    u.z = pack_bf16(p[512], p[640]);
    u.w = pack_bf16(p[768], p[896]);
    VF[(size_t)((b * 64 + T) * 8 + dt) * 64 + lane] = u;
  }
}

// ---------------------------------------------------------------------------
// Main kernel: 32 m-rows per block; 4 waves each owning a 512-col N-quarter,
// processing TWO 16-row m-slabs so each kf/vf fragment load feeds 2x MFMA.
// ---------------------------------------------------------------------------
__launch_bounds__(256, 2)
__global__ void attn7_kernel(const float* __restrict__ x1,
                             const uint4* __restrict__ KF,
                             const uint4* __restrict__ VF,
                             float* __restrict__ out) {
  // LDS 8832 words = 35328B.
  // Main loop: Pb [0..2560): 4 waves x 640 words (2 slabs x 320, private).
  // Epilogue (aliases all): EP 8192 f + EPL 576 f, one slab-pass at a time.
  __shared__ __attribute__((aligned(16))) uint32_t SMEM[8832];

  const int tid = threadIdx.x;
  const int w = __builtin_amdgcn_readfirstlane(tid >> 6);   // N-quarter 0..3
  const int lane = tid & 63;
  const int l15 = lane & 15;
  const int g = lane >> 4;
  // XCD batch swizzle: b = id&7 -> one batch per XCD (2MB slice L2-resident).
  const int id = blockIdx.y * 64 + blockIdx.x;
  const int b = id & 7;
  const int mt = id >> 3;       // 0..63
  const int m0 = mt * 32;
  // Tile-phase stagger (R9-proven): desync co-resident stall points.
  const int t0 = (mt + w) & 15;

  uint32_t* PbW = &SMEM[w * 640];   // 2 slabs x 320 words

  // ---- Q fragments for both slabs (B-operand: l15 -> m), x 0.5*log2(e) ----
  const float QSCALE = 0.5f * 1.44269504088896340736f;
  bf16x8 qf[2][4];
  #pragma unroll
  for (int s = 0; s < 2; ++s) {
    const float* qp_base = x1 + ((size_t)b * 2048 + m0 + s * 16 + l15) * 128;
    #pragma unroll
    for (int c = 0; c < 4; ++c) {
      const float* qp = qp_base + c * 32 + g * 8;
      float4 f0 = *(const float4*)(qp);
      float4 f1 = *(const float4*)(qp + 4);
      uint4 u;
      u.x = pack_bf16(f0.x * QSCALE, f0.y * QSCALE);
      u.y = pack_bf16(f0.z * QSCALE, f0.w * QSCALE);
      u.z = pack_bf16(f1.x * QSCALE, f1.y * QSCALE);
      u.w = pack_bf16(f1.z * QSCALE, f1.w * QSCALE);
      qf[s][c] = __builtin_bit_cast(bf16x8, u);
    }
  }

  f32x4 o[2][8];
  #pragma unroll
  for (int s = 0; s < 2; ++s)
    #pragma unroll
    for (int dt = 0; dt < 8; ++dt) o[s][dt] = (f32x4){0.f, 0.f, 0.f, 0.f};
  float lsum[2] = {0.f, 0.f};

  // RNG row base per slab, per-lane 4g folded in: in1 = rb[s] + tt*32+t*16+r.
  uint32_t rb[2];
  #pragma unroll
  for (int s = 0; s < 2; ++s)
    rb[s] = (uint32_t)b * 4194304u +
            (uint32_t)(m0 + s * 16 + l15) * 2048u + (uint32_t)(w * 512) +
            (uint32_t)(4 * g);

  const uint4* kfb = KF + (size_t)((b * 64 + w * 16) * 8) * 64 + lane;
  const uint4* vfb = VF + (size_t)((b * 64 + w * 16) * 8) * 64 + lane;

  for (int tile = 0; tile < 16; ++tile) {
    const int tt = (t0 + tile) & 15;
    const uint4* kfp = kfb + (size_t)tt * 512;
    const uint4* vfp = vfb + (size_t)tt * 512;

    // ---- S^T = K Q^T for BOTH slabs: each kf load feeds 2 MFMAs ----
    f32x4 sa[2][2];
    #pragma unroll
    for (int s = 0; s < 2; ++s) {
      sa[s][0] = (f32x4){0.f, 0.f, 0.f, 0.f};
      sa[s][1] = (f32x4){0.f, 0.f, 0.f, 0.f};
    }
    __builtin_amdgcn_s_setprio(1);
    #pragma unroll
    for (int c = 0; c < 4; ++c) {
      bf16x8 k0 = __builtin_bit_cast(bf16x8, kfp[(c * 2 + 0) * 64]);
      bf16x8 k1 = __builtin_bit_cast(bf16x8, kfp[(c * 2 + 1) * 64]);
      sa[0][0] = __builtin_amdgcn_mfma_f32_16x16x32_bf16(k0, qf[0][c], sa[0][0], 0, 0, 0);
      sa[0][1] = __builtin_amdgcn_mfma_f32_16x16x32_bf16(k1, qf[0][c], sa[0][1], 0, 0, 0);
      sa[1][0] = __builtin_amdgcn_mfma_f32_16x16x32_bf16(k0, qf[1][c], sa[1][0], 0, 0, 0);
      sa[1][1] = __builtin_amdgcn_mfma_f32_16x16x32_bf16(k1, qf[1][c], sa[1][1], 0, 0, 0);
    }
    __builtin_amdgcn_s_setprio(0);

    // ---- softmax (unbiased exp2; 2^bias cancels in L) + inline threefry
    //      dropout for both slabs; both P slabs stored, ONE fence ----
    #pragma unroll
    for (int s = 0; s < 2; ++s) {
      #pragma unroll
      for (int t = 0; t < 2; ++t) {
        float p0 = __builtin_amdgcn_exp2f(sa[s][t][0]);
        float p1 = __builtin_amdgcn_exp2f(sa[s][t][1]);
        float p2 = __builtin_amdgcn_exp2f(sa[s][t][2]);
        float p3 = __builtin_amdgcn_exp2f(sa[s][t][3]);
        lsum[s] += (p0 + p1) + (p2 + p3);   // denominator: UNMASKED probs
        const uint32_t ib = rb[s] + (uint32_t)(tt * 32 + t * 16);
        uint32_t h0, h1, bits;
        threefry2x32_k42(0u, ib + 0u, h0, h1); bits = h0 ^ h1;
        float q0 = (bits < KEEP_LT) ? p0 : 0.0f;
        threefry2x32_k42(0u, ib + 1u, h0, h1); bits = h0 ^ h1;
        float q1 = (bits < KEEP_LT) ? p1 : 0.0f;
        threefry2x32_k42(0u, ib + 2u, h0, h1); bits = h0 ^ h1;
        float q2 = (bits < KEEP_LT) ? p2 : 0.0f;
        threefry2x32_k42(0u, ib + 3u, h0, h1); bits = h0 ^ h1;
        float q3 = (bits < KEEP_LT) ? p3 : 0.0f;
        *(uint2*)&PbW[s * 320 + l15 * 20 + t * 8 + 2 * g] =
            make_uint2(pack_bf16(q0, q1), pack_bf16(q2, q3));
      }
    }
    asm volatile("s_waitcnt lgkmcnt(0)" ::: "memory");  // in-order DS per wave
    uint4 pu0 = *(const uint4*)&PbW[l15 * 20 + 4 * g];
    uint4 pu1 = *(const uint4*)&PbW[320 + l15 * 20 + 4 * g];
    bf16x8 pa0 = __builtin_bit_cast(bf16x8, pu0);
    bf16x8 pa1 = __builtin_bit_cast(bf16x8, pu1);

    // ---- O += P V : each vf load feeds 2 MFMAs (both slabs) ----
    __builtin_amdgcn_s_setprio(1);
    #pragma unroll
    for (int dt = 0; dt < 8; ++dt) {
      bf16x8 vb = __builtin_bit_cast(bf16x8, vfp[dt * 64]);
      o[0][dt] = __builtin_amdgcn_mfma_f32_16x16x32_bf16(pa0, vb, o[0][dt], 0, 0, 0);
      o[1][dt] = __builtin_amdgcn_mfma_f32_16x16x32_bf16(pa1, vb, o[1][dt], 0, 0, 0);
    }
    __builtin_amdgcn_s_setprio(0);
  }

  // ---- epilogue: two slab passes of the proven 4-quarter merge ----
  float* EP = (float*)&SMEM[0];
  float* EPL = EP + 8192;
  #pragma unroll
  for (int s = 0; s < 2; ++s) {
    __syncthreads();   // pass0: Pb->EP handoff; pass1: reads-done->overwrite
    // L partials: row m (16) x (quarter*4+g), stride 36 (conflict-free)
    EPL[l15 * 36 + w * 4 + g] = lsum[s];
    // O partials: [(w*8+dt)*4+r] x lane (stride-1, conflict-free). 8192 f.
    #pragma unroll
    for (int dt = 0; dt < 8; ++dt)
      #pragma unroll
      for (int r = 0; r < 4; ++r)
        EP[((w * 8 + dt) * 4 + r) * 64 + lane] = o[s][dt][r];
    __syncthreads();
    float scale[4];
    #pragma unroll
    for (int r = 0; r < 4; ++r) {
      const float4* lp = (const float4*)&EPL[(4 * g + r) * 36];
      float4 A = lp[0], B4 = lp[1], C4 = lp[2], D4 = lp[3];
      float L = ((A.x + A.y) + (A.z + A.w)) + ((B4.x + B4.y) + (B4.z + B4.w)) +
                ((C4.x + C4.y) + (C4.z + C4.w)) + ((D4.x + D4.y) + (D4.z + D4.w));
      scale[r] = 1.0f / (L * 0.8f);
    }
    #pragma unroll
    for (int i = 0; i < 2; ++i) {
      const int dt = w * 2 + i;
      #pragma unroll
      for (int r = 0; r < 4; ++r) {
        int base = (dt * 4 + r) * 64 + lane;
        float tot = EP[base] + EP[base + 2048] + EP[base + 4096] + EP[base + 6144];
        out[((size_t)b * 2048 + m0 + s * 16 + 4 * g + r) * 128 + dt * 16 + l15] =
            tot * scale[r];
      }
    }
  }
}

// ---------------------------------------------------------------------------
// Fallback (R4, harness-verified 107us): used only if workspace < 8MB.
// ---------------------------------------------------------------------------
union FragAB {
  bf16x8 v;
  uint32_t u[4];
};

__launch_bounds__(256, 2)
__global__ void attn_kernel(const float* __restrict__ x1,
                            const float* __restrict__ x2,
                            float* __restrict__ out) {
  __shared__ __attribute__((aligned(16))) uint32_t SMEM[4][4800];

  const int tid = threadIdx.x;
  const int wv = __builtin_amdgcn_readfirstlane(tid >> 6);
  const int lane = tid & 63;
  const int l15 = lane & 15;
  const int g = lane >> 4;
  const int b = blockIdx.y;
  const int m0 = blockIdx.x * 32;

  uint32_t* KtW = &SMEM[wv][0];
  uint32_t* VtW = &SMEM[wv][2176];
  uint32_t* PbW = &SMEM[wv][4480];

  const float QSCALE = 0.5f * 1.44269504088896340736f;
  FragAB qf[2][4];
  #pragma unroll
  for (int s = 0; s < 2; ++s) {
    const float* qp_base = x1 + ((size_t)b * 2048 + m0 + s * 16 + l15) * 128;
    #pragma unroll
    for (int c = 0; c < 4; ++c) {
      const float* qp = qp_base + c * 32 + g * 8;
      float4 f0 = *(const float4*)(qp);
      float4 f1 = *(const float4*)(qp + 4);
      qf[s][c].u[0] = pack_bf16(f0.x * QSCALE, f0.y * QSCALE);
      qf[s][c].u[1] = pack_bf16(f0.z * QSCALE, f0.w * QSCALE);
      qf[s][c].u[2] = pack_bf16(f1.x * QSCALE, f1.y * QSCALE);
      qf[s][c].u[3] = pack_bf16(f1.z * QSCALE, f1.w * QSCALE);
    }
  }

  f32x4 o[2][8];
  #pragma unroll
  for (int s = 0; s < 2; ++s)
    #pragma unroll
    for (int dt = 0; dt < 8; ++dt) o[s][dt] = (f32x4){0.f, 0.f, 0.f, 0.f};
  float lsum[2] = {0.f, 0.f};

  uint32_t rb[2];
  #pragma unroll
  for (int s = 0; s < 2; ++s)
    rb[s] = (uint32_t)b * 4194304u +
            (uint32_t)(m0 + s * 16 + l15) * 2048u + (uint32_t)(wv * 512);

  const float4* x2b4 = (const float4*)(x2 + (size_t)b * 2048 * 128);
  const uint32_t permsel = (l15 & 1) ? 0x07060302u : 0x05040100u;

  for (int tile = 0; tile < 16; ++tile) {
    const int n0g = wv * 512 + tile * 32;

    #pragma unroll
    for (int i = 0; i < 16; ++i) {
      int n = 2 * i + (lane >> 5);
      int dq = lane & 31;
      float4 v = x2b4[(size_t)(n0g + n) * 32 + dq];
      uint32_t p0 = pack_bf16(v.x, v.y);
      uint32_t p1 = pack_bf16(v.z, v.w);
      *(uint2*)&KtW[n * 68 + 2 * dq] = make_uint2(p0, p1);
      VtW[dq * 36 + n] = p0;
      VtW[(dq + 32) * 36 + n] = p1;
    }
    asm volatile("s_waitcnt lgkmcnt(0)" ::: "memory");

    f32x4 sa[2][2];
    #pragma unroll
    for (int s = 0; s < 2; ++s)
      #pragma unroll
      for (int t = 0; t < 2; ++t) sa[s][t] = (f32x4){0.f, 0.f, 0.f, 0.f};
    #pragma unroll
    for (int c = 0; c < 4; ++c) {
      FragAB k0, k1;
      uint4 a0 = *(const uint4*)&KtW[l15 * 68 + c * 16 + 4 * g];
      uint4 a1 = *(const uint4*)&KtW[(16 + l15) * 68 + c * 16 + 4 * g];
      k0.u[0] = a0.x; k0.u[1] = a0.y; k0.u[2] = a0.z; k0.u[3] = a0.w;
      k1.u[0] = a1.x; k1.u[1] = a1.y; k1.u[2] = a1.z; k1.u[3] = a1.w;
      sa[0][0] = __builtin_amdgcn_mfma_f32_16x16x32_bf16(k0.v, qf[0][c].v, sa[0][0], 0, 0, 0);
      sa[0][1] = __builtin_amdgcn_mfma_f32_16x16x32_bf16(k1.v, qf[0][c].v, sa[0][1], 0, 0, 0);
      sa[1][0] = __builtin_amdgcn_mfma_f32_16x16x32_bf16(k0.v, qf[1][c].v, sa[1][0], 0, 0, 0);
      sa[1][1] = __builtin_amdgcn_mfma_f32_16x16x32_bf16(k1.v, qf[1][c].v, sa[1][1], 0, 0, 0);
    }

    FragAB pa[2];
    #pragma unroll
    for (int s = 0; s < 2; ++s) {
      #pragma unroll
      for (int t = 0; t < 2; ++t) {
        float p0 = __builtin_amdgcn_exp2f(sa[s][t][0] - MBIAS);
        float p1 = __builtin_amdgcn_exp2f(sa[s][t][1] - MBIAS);
        float p2 = __builtin_amdgcn_exp2f(sa[s][t][2] - MBIAS);
        float p3 = __builtin_amdgcn_exp2f(sa[s][t][3] - MBIAS);
        lsum[s] += (p0 + p1) + (p2 + p3);
        uint32_t ib = rb[s] + (uint32_t)(tile * 32 + t * 16 + 4 * g);
        uint32_t h0, h1, bits;
        threefry2x32_k42(0u, ib + 0u, h0, h1); bits = h0 ^ h1;
        float q0 = (bits < KEEP_LT) ? p0 : 0.0f;
        threefry2x32_k42(0u, ib + 1u, h0, h1); bits = h0 ^ h1;
        float q1 = (bits < KEEP_LT) ? p1 : 0.0f;
        threefry2x32_k42(0u, ib + 2u, h0, h1); bits = h0 ^ h1;
        float q2 = (bits < KEEP_LT) ? p2 : 0.0f;
        threefry2x32_k42(0u, ib + 3u, h0, h1); bits = h0 ^ h1;
        float q3 = (bits < KEEP_LT) ? p3 : 0.0f;
        *(uint2*)&PbW[l15 * 20 + t * 8 + 2 * g] =
            make_uint2(pack_bf16(q0, q1), pack_bf16(q2, q3));
      }
      asm volatile("s_waitcnt lgkmcnt(0)" ::: "memory");
      uint4 pu = *(const uint4*)&PbW[l15 * 20 + 4 * g];
      pa[s].u[0] = pu.x; pa[s].u[1] = pu.y; pa[s].u[2] = pu.z; pa[s].u[3] = pu.w;
    }

    #pragma unroll
    for (int dt = 0; dt < 8; ++dt) {
      int rowp = ((l15 >> 1) & 1) * 32 + 4 * dt + (l15 >> 2);
      const uint32_t* vr = &VtW[rowp * 36 + 8 * g];
      uint4 U0 = *(const uint4*)vr;
      uint4 U1 = *(const uint4*)(vr + 4);
      FragAB vb;
      vb.u[0] = __builtin_amdgcn_perm(U0.y, U0.x, permsel);
      vb.u[1] = __builtin_amdgcn_perm(U0.w, U0.z, permsel);
      vb.u[2] = __builtin_amdgcn_perm(U1.y, U1.x, permsel);
      vb.u[3] = __builtin_amdgcn_perm(U1.w, U1.z, permsel);
      o[0][dt] = __builtin_amdgcn_mfma_f32_16x16x32_bf16(pa[0].v, vb.v, o[0][dt], 0, 0, 0);
      o[1][dt] = __builtin_amdgcn_mfma_f32_16x16x32_bf16(pa[1].v, vb.v, o[1][dt], 0, 0, 0);
    }
  }

  __syncthreads();
  float* EP = (float*)&SMEM[0][0];
  #pragma unroll
  for (int s = 0; s < 2; ++s) {
    #pragma unroll
    for (int dt = 0; dt < 8; ++dt)
      #pragma unroll
      for (int r = 0; r < 4; ++r)
        EP[(((wv * 2 + s) * 8 + dt) * 4 + r) * 64 + lane] = o[s][dt][r];
    EP[16384 + (s * 16 + l15) * 16 + wv * 4 + g] = lsum[s];
  }
  __syncthreads();
  const int s = wv >> 1;
  float scale[4];
  #pragma unroll
  for (int r = 0; r < 4; ++r) {
    const float4* lp = (const float4*)&EP[16384 + (s * 16 + 4 * g + r) * 16];
    float4 A = lp[0], B4 = lp[1], C4 = lp[2], D4 = lp[3];
    float L = ((A.x + A.y) + (A.z + A.w)) + ((B4.x + B4.y) + (B4.z + B4.w)) +
              ((C4.x + C4.y) + (C4.z + C4.w)) + ((D4.x + D4.y) + (D4.z + D4.w));
    scale[r] = 1.0f / (L * 0.8f);
  }
  #pragma unroll
  for (int it = 0; it < 4; ++it) {
    int dt = (wv * 4 + it) & 7;
    #pragma unroll
    for (int r = 0; r < 4; ++r) {
      int base = ((s * 8 + dt) * 4 + r) * 64 + lane;
      float tot = EP[base] + EP[base + 4096] + EP[base + 8192] + EP[base + 12288];
      out[((size_t)b * 2048 + m0 + s * 16 + 4 * g + r) * 128 + dt * 16 + l15] =
          tot * scale[r];
    }
  }
}

extern "C" void kernel_launch(void* const* d_in, const int* in_sizes, int n_in,
                              void* d_out, int out_size, void* d_ws, size_t ws_size,
                              hipStream_t stream) {
  const float* x1 = (const float*)d_in[0];
  const float* x2 = (const float*)d_in[1];
  float* out = (float*)d_out;
  if (d_ws != nullptr && ws_size >= (size_t)8 * 1024 * 1024) {
    uint4* KF = (uint4*)d_ws;
    uint4* VF = KF + 262144;   // +4MB
    prep_kernel<<<dim3(64, 8, 1), dim3(256, 1, 1), 0, stream>>>(x2, KF, VF);
    attn7_kernel<<<dim3(64, 8, 1), dim3(256, 1, 1), 0, stream>>>(x1, KF, VF, out);
  } else {
    attn_kernel<<<dim3(64, 8, 1), dim3(256, 1, 1), 0, stream>>>(x1, x2, out);
  }
}

// Round 12
// 143.874 us; speedup vs baseline: 1.3572x; 1.0632x over previous
//
#include <hip/hip_runtime.h>
#include <stdint.h>

// ---------------------------------------------------------------------------
// Fused attention: out = dropout(softmax(0.5 * x1 @ x2^T), p=0.2, jax key 42) @ x2
// B=8, M=N=2048, D=128, fp32 in/out. bf16 MFMA (16x16x32), bitwise JAX threefry
// (partitionable form: bits = h0^h1 of threefry((0,42),(0,flat_idx))).
//
// R16 = R9 reverted EXACTLY (R15 crashed from a transcription bug: prep grid
// was accidentally 128x8, overrunning the 8MB workspace by 2x — prep_kernel's
// blockIdx.x indexes 64 n-tiles. Restored to dim3(64,8)).
//
// Roofline evidence (R10/R11/R14):
//  - maskgen alone (pure threefry, no memory, 8 indep chains/SIMD, VALUBusy
//    83%) = 90us. Fused attn2 = 90.5us doing the SAME RNG volume PLUS all
//    attention work (MfmaUtil 7%, HBM 2%) -> attention rides entirely inside
//    the mandatory RNG issue schedule.
//  - All structural variants (8 waves/SIMD R10, threefry-split R11,
//    barrier-share R12, request-halving R14) land 90-95us; scheduling levers
//    move <=3%.
//  - Floor op: bit-exact JAX threefry mask, ~75 VALU inst x 33.5M elems =
//    2.5G instructions at the measured effective issue rate = ~75-90us.
// ---------------------------------------------------------------------------

typedef __bf16 bf16x8 __attribute__((ext_vector_type(8)));
typedef float f32x4 __attribute__((ext_vector_type(4)));

__device__ __forceinline__ uint32_t rotl32(uint32_t x, uint32_t r) {
  return (x << r) | (x >> (32u - r));   // -> v_alignbit_b32
}

// JAX threefry2x32 with key (0, 42)
__device__ __forceinline__ void threefry2x32_k42(uint32_t in0, uint32_t in1,
                                                 uint32_t& o0, uint32_t& o1) {
  const uint32_t ks0 = 0u;
  const uint32_t ks1 = 42u;
  const uint32_t ks2 = 0x1BD11BDAu ^ 0u ^ 42u;
  uint32_t x0 = in0 + ks0;
  uint32_t x1 = in1 + ks1;
#define TFR(r) { x0 += x1; x1 = rotl32(x1, r); x1 ^= x0; }
  TFR(13u) TFR(15u) TFR(26u) TFR(6u)
  x0 += ks1; x1 += ks2 + 1u;
  TFR(17u) TFR(29u) TFR(16u) TFR(24u)
  x0 += ks2; x1 += ks0 + 2u;
  TFR(13u) TFR(15u) TFR(26u) TFR(6u)
  x0 += ks0; x1 += ks1 + 3u;
  TFR(17u) TFR(29u) TFR(16u) TFR(24u)
  x0 += ks1; x1 += ks2 + 4u;
  TFR(13u) TFR(15u) TFR(26u) TFR(6u)
  x0 += ks2; x1 += ks0 + 5u;
#undef TFR
  o0 = x0; o1 = x1;
}

__device__ __forceinline__ uint32_t pack_bf16(float a, float b) {
  __bf16 ba = (__bf16)a;   // RTNE
  __bf16 bb = (__bf16)b;
  uint32_t ua = (uint32_t)__builtin_bit_cast(uint16_t, ba);
  uint32_t ub = (uint32_t)__builtin_bit_cast(uint16_t, bb);
  return ua | (ub << 16);
}

// keep iff uniform < 0.8f  <=>  bits < 6710887<<9
#define KEEP_LT 3435974144u
#define MBIAS 40.0f   // used only by the fallback kernel

// ---------------------------------------------------------------------------
// Prepass: pack x2 (f32) into fragment-ordered bf16 layouts in workspace.
//   KF[((b*64+T)*8 + c*2+h)*64 + lane] (uint4):
//     A-frag for QK^T: rows n = T*32 + h*16 + l15, 8 bf16 at d = c*32+8g..+7
//   VF[((b*64+T)*8 + dt)*64 + lane] (uint4):
//     B-frag for PV: u[j] = pack(x2[T*32+8g+2j][dt*16+l15], x2[..+2j+1][..])
// Each 4MB, total 8MB. Grid MUST be dim3(64, 8): blockIdx.x = T in [0,64).
// ---------------------------------------------------------------------------
__launch_bounds__(256, 4)
__global__ void prep_kernel(const float* __restrict__ x2,
                            uint4* __restrict__ KF,
                            uint4* __restrict__ VF) {
  const int tid = threadIdx.x;
  const int w = tid >> 6;        // 0..3  (= c for KF; = dt base for VF)
  const int lane = tid & 63;
  const int l15 = lane & 15;
  const int g = lane >> 4;
  const int T = blockIdx.x;      // 0..63 (32-row n-tile)
  const int b = blockIdx.y;
  const float* xb = x2 + (size_t)b * 2048 * 128;

  // KF: this wave handles c = w, h = 0,1
  #pragma unroll
  for (int h = 0; h < 2; ++h) {
    const int n = T * 32 + h * 16 + l15;
    const float* p = xb + (size_t)n * 128 + w * 32 + 8 * g;
    float4 f0 = *(const float4*)(p);
    float4 f1 = *(const float4*)(p + 4);
    uint4 u;
    u.x = pack_bf16(f0.x, f0.y);
    u.y = pack_bf16(f0.z, f0.w);
    u.z = pack_bf16(f1.x, f1.y);
    u.w = pack_bf16(f1.z, f1.w);
    KF[(size_t)((b * 64 + T) * 8 + w * 2 + h) * 64 + lane] = u;
  }

  // VF: this wave handles dt = w and w+4
  #pragma unroll
  for (int i = 0; i < 2; ++i) {
    const int dt = w + 4 * i;
    const int d = dt * 16 + l15;
    const float* p = xb + (size_t)(T * 32 + 8 * g) * 128 + d;
    uint4 u;
    u.x = pack_bf16(p[0],   p[128]);
    u.y = pack_bf16(p[256], p[384]);
    u.z = pack_bf16(p[512], p[640]);
    u.w = pack_bf16(p[768], p[896]);
    VF[(size_t)((b * 64 + T) * 8 + dt) * 64 + lane] = u;
  }
}

// ---------------------------------------------------------------------------
// Main kernel: 16 m-rows per block, 4 waves each owning a 512-col N-quarter.
// ---------------------------------------------------------------------------
__launch_bounds__(256, 4)
__global__ void attn2_kernel(const float* __restrict__ x1,
                             const uint4* __restrict__ KF,
                             const uint4* __restrict__ VF,
                             float* __restrict__ out) {
  // LDS: Pb 4 waves x 320 words (main loop, wave-private) aliased with
  // epilogue: EP 8192 f (O partials) + EPL 16x36 f (L partials) = 8768 f.
  __shared__ __attribute__((aligned(16))) uint32_t SMEM[8768];

  const int tid = threadIdx.x;
  const int w = __builtin_amdgcn_readfirstlane(tid >> 6);   // N-quarter
  const int lane = tid & 63;
  const int l15 = lane & 15;
  const int g = lane >> 4;
  // XCD batch-locality swizzle: with round-robin XCD dispatch (xcd = id%8),
  // b = id&7 puts all 128 m-blocks of one batch on one XCD -> 2MB KF/VF
  // slice is L2-resident (FETCH 37->8MB measured R6/R8).
  const int id = blockIdx.y * 128 + blockIdx.x;
  const int b = id & 7;
  const int mt = id >> 3;
  const int m0 = mt * 16;
  // Tile-phase stagger: co-resident blocks (same b, different mt) start at
  // different K/V tiles -> stall points desync instead of convoying.
  const int t0 = mt & 15;

  uint32_t* PbW = &SMEM[w * 320];   // P transpose buffer: row m (16), 20 words

  // ---- Q fragments (B-operand: l15 -> m), scaled by 0.5*log2(e) ----
  const float QSCALE = 0.5f * 1.44269504088896340736f;
  bf16x8 qfv[4];
  {
    const float* qp_base = x1 + ((size_t)b * 2048 + m0 + l15) * 128;
    #pragma unroll
    for (int c = 0; c < 4; ++c) {
      const float* qp = qp_base + c * 32 + g * 8;
      float4 f0 = *(const float4*)(qp);
      float4 f1 = *(const float4*)(qp + 4);
      uint4 u;
      u.x = pack_bf16(f0.x * QSCALE, f0.y * QSCALE);
      u.y = pack_bf16(f0.z * QSCALE, f0.w * QSCALE);
      u.z = pack_bf16(f1.x * QSCALE, f1.y * QSCALE);
      u.w = pack_bf16(f1.z * QSCALE, f1.w * QSCALE);
      qfv[c] = __builtin_bit_cast(bf16x8, u);
    }
  }

  f32x4 o[8];
  #pragma unroll
  for (int dt = 0; dt < 8; ++dt) o[dt] = (f32x4){0.f, 0.f, 0.f, 0.f};
  float lsum = 0.f;

  // RNG row base with the per-lane 4g folded in: element (tt,t,r) has
  // in1 = rbg + tt*32 + t*16 + r.
  const uint32_t rbg = (uint32_t)b * 4194304u +
                       (uint32_t)(m0 + l15) * 2048u + (uint32_t)(w * 512) +
                       (uint32_t)(4 * g);

  const uint4* kfb = KF + (size_t)((b * 64 + w * 16) * 8) * 64 + lane;
  const uint4* vfb = VF + (size_t)((b * 64 + w * 16) * 8) * 64 + lane;

  // ---- mask pipeline: {0,1} floats for the CURRENT tile, generated one
  // tile ahead so the serial threefry chain never sits between QK and PV.
  float mcur[8], mnext[8];
  #pragma unroll
  for (int j = 0; j < 8; ++j) mnext[j] = 0.f;
  #pragma unroll
  for (int t = 0; t < 2; ++t)
    #pragma unroll
    for (int r = 0; r < 4; ++r) {
      uint32_t h0, h1;
      threefry2x32_k42(0u, rbg + (uint32_t)(t0 * 32 + t * 16 + r), h0, h1);
      mcur[t * 4 + r] = ((h0 ^ h1) < KEEP_LT) ? 1.0f : 0.0f;
    }

  for (int tile = 0; tile < 16; ++tile) {
    const int tt = (t0 + tile) & 15;          // this wave's tile this iter
    const uint4* kfp = kfb + (size_t)tt * 512;
    const uint4* vfp = vfb + (size_t)tt * 512;

    // ---- S^T = K Q^T : C/D row = n (4g+r), col = m (l15). ----
    f32x4 sa[2];
    sa[0] = (f32x4){0.f, 0.f, 0.f, 0.f};
    sa[1] = (f32x4){0.f, 0.f, 0.f, 0.f};
    __builtin_amdgcn_s_setprio(1);
    #pragma unroll
    for (int c = 0; c < 4; ++c) {
      bf16x8 k0 = __builtin_bit_cast(bf16x8, kfp[(c * 2 + 0) * 64]);
      bf16x8 k1 = __builtin_bit_cast(bf16x8, kfp[(c * 2 + 1) * 64]);
      sa[0] = __builtin_amdgcn_mfma_f32_16x16x32_bf16(k0, qfv[c], sa[0], 0, 0, 0);
      sa[1] = __builtin_amdgcn_mfma_f32_16x16x32_bf16(k1, qfv[c], sa[1], 0, 0, 0);
    }
    __builtin_amdgcn_s_setprio(0);

    // ---- V prefetch for THIS tile, pinned by sched_barrier so the
    // scheduler cannot sink it: lands under the ~1300cy threefry block.
    uint4 vf[8];
    #pragma unroll
    for (int dt = 0; dt < 8; ++dt) vf[dt] = vfp[dt * 64];
    __builtin_amdgcn_sched_barrier(0);

    // ---- softmax (unbiased exp2: uniform 2^bias scale cancels in L) +
    //      mask apply (1 mul) + P -> Pbuf ----
    #pragma unroll
    for (int t = 0; t < 2; ++t) {
      float p0 = __builtin_amdgcn_exp2f(sa[t][0]);
      float p1 = __builtin_amdgcn_exp2f(sa[t][1]);
      float p2 = __builtin_amdgcn_exp2f(sa[t][2]);
      float p3 = __builtin_amdgcn_exp2f(sa[t][3]);
      lsum += (p0 + p1) + (p2 + p3);   // denominator uses UNMASKED probs
      float q0 = p0 * mcur[t * 4 + 0];
      float q1 = p1 * mcur[t * 4 + 1];
      float q2 = p2 * mcur[t * 4 + 2];
      float q3 = p3 * mcur[t * 4 + 3];
      *(uint2*)&PbW[l15 * 20 + t * 8 + 2 * g] =
          make_uint2(pack_bf16(q0, q1), pack_bf16(q2, q3));
    }

    // ---- generate NEXT tile's mask: free-floating ALU, no consumer this
    // tile -> overlaps the DS fence / PV below and feeds the issue slots
    // other waves stall in.
    if (tile < 15) {
      const uint32_t base = rbg + (uint32_t)(((t0 + tile + 1) & 15) * 32);
      #pragma unroll
      for (int t = 0; t < 2; ++t)
        #pragma unroll
        for (int r = 0; r < 4; ++r) {
          uint32_t h0, h1;
          threefry2x32_k42(0u, base + (uint32_t)(t * 16 + r), h0, h1);
          mnext[t * 4 + r] = ((h0 ^ h1) < KEEP_LT) ? 1.0f : 0.0f;
        }
    }

    asm volatile("s_waitcnt lgkmcnt(0)" ::: "memory");  // in-order DS per wave
    uint4 pu = *(const uint4*)&PbW[l15 * 20 + 4 * g];   // A-frag: m=l15, k=8g+j
    bf16x8 pav = __builtin_bit_cast(bf16x8, pu);

    // ---- O += P V : V B-frags already in registers ----
    __builtin_amdgcn_s_setprio(1);
    #pragma unroll
    for (int dt = 0; dt < 8; ++dt) {
      bf16x8 vb = __builtin_bit_cast(bf16x8, vf[dt]);
      o[dt] = __builtin_amdgcn_mfma_f32_16x16x32_bf16(pav, vb, o[dt], 0, 0, 0);
    }
    __builtin_amdgcn_s_setprio(0);

    #pragma unroll
    for (int j = 0; j < 8; ++j) mcur[j] = mnext[j];
  }

  // ---- epilogue: plain-sum merge of 4 N-quarters ----
  __syncthreads();   // all waves done with their private Pb regions
  float* EP = (float*)&SMEM[0];
  float* EPL = EP + 8192;
  // L partials: row m (16) x (quarter*4+g), stride 36 (pad: conflict-free)
  EPL[l15 * 36 + w * 4 + g] = lsum;
  // O partials: [(w*8+dt)*4+r] x lane (stride-1, conflict-free). 8192 f.
  #pragma unroll
  for (int dt = 0; dt < 8; ++dt)
    #pragma unroll
    for (int r = 0; r < 4; ++r)
      EP[((w * 8 + dt) * 4 + r) * 64 + lane] = o[dt][r];
  __syncthreads();
  float scale[4];
  #pragma unroll
  for (int r = 0; r < 4; ++r) {
    const float4* lp = (const float4*)&EPL[(4 * g + r) * 36];
    float4 A = lp[0], B4 = lp[1], C4 = lp[2], D4 = lp[3];
    float L = ((A.x + A.y) + (A.z + A.w)) + ((B4.x + B4.y) + (B4.z + B4.w)) +
              ((C4.x + C4.y) + (C4.z + C4.w)) + ((D4.x + D4.y) + (D4.z + D4.w));
    scale[r] = 1.0f / (L * 0.8f);
  }
  #pragma unroll
  for (int i = 0; i < 2; ++i) {
    const int dt = w * 2 + i;
    #pragma unroll
    for (int r = 0; r < 4; ++r) {
      int base = (dt * 4 + r) * 64 + lane;
      float tot = EP[base] + EP[base + 2048] + EP[base + 4096] + EP[base + 6144];
      out[((size_t)b * 2048 + m0 + 4 * g + r) * 128 + dt * 16 + l15] =
          tot * scale[r];
    }
  }
}

// ---------------------------------------------------------------------------
// Fallback (R4, harness-verified 107us): used only if workspace < 8MB.
// ---------------------------------------------------------------------------
union FragAB {
  bf16x8 v;
  uint32_t u[4];
};

__launch_bounds__(256, 2)
__global__ void attn_kernel(const float* __restrict__ x1,
                            const float* __restrict__ x2,
                            float* __restrict__ out) {
  __shared__ __attribute__((aligned(16))) uint32_t SMEM[4][4800];

  const int tid = threadIdx.x;
  const int wv = __builtin_amdgcn_readfirstlane(tid >> 6);
  const int lane = tid & 63;
  const int l15 = lane & 15;
  const int g = lane >> 4;
  const int b = blockIdx.y;
  const int m0 = blockIdx.x * 32;

  uint32_t* KtW = &SMEM[wv][0];
  uint32_t* VtW = &SMEM[wv][2176];
  uint32_t* PbW = &SMEM[wv][4480];

  const float QSCALE = 0.5f * 1.44269504088896340736f;
  FragAB qf[2][4];
  #pragma unroll
  for (int s = 0; s < 2; ++s) {
    const float* qp_base = x1 + ((size_t)b * 2048 + m0 + s * 16 + l15) * 128;
    #pragma unroll
    for (int c = 0; c < 4; ++c) {
      const float* qp = qp_base + c * 32 + g * 8;
      float4 f0 = *(const float4*)(qp);
      float4 f1 = *(const float4*)(qp + 4);
      qf[s][c].u[0] = pack_bf16(f0.x * QSCALE, f0.y * QSCALE);
      qf[s][c].u[1] = pack_bf16(f0.z * QSCALE, f0.w * QSCALE);
      qf[s][c].u[2] = pack_bf16(f1.x * QSCALE, f1.y * QSCALE);
      qf[s][c].u[3] = pack_bf16(f1.z * QSCALE, f1.w * QSCALE);
    }
  }

  f32x4 o[2][8];
  #pragma unroll
  for (int s = 0; s < 2; ++s)
    #pragma unroll
    for (int dt = 0; dt < 8; ++dt) o[s][dt] = (f32x4){0.f, 0.f, 0.f, 0.f};
  float lsum[2] = {0.f, 0.f};

  uint32_t rb[2];
  #pragma unroll
  for (int s = 0; s < 2; ++s)
    rb[s] = (uint32_t)b * 4194304u +
            (uint32_t)(m0 + s * 16 + l15) * 2048u + (uint32_t)(wv * 512);

  const float4* x2b4 = (const float4*)(x2 + (size_t)b * 2048 * 128);
  const uint32_t permsel = (l15 & 1) ? 0x07060302u : 0x05040100u;

  for (int tile = 0; tile < 16; ++tile) {
    const int n0g = wv * 512 + tile * 32;

    #pragma unroll
    for (int i = 0; i < 16; ++i) {
      int n = 2 * i + (lane >> 5);
      int dq = lane & 31;
      float4 v = x2b4[(size_t)(n0g + n) * 32 + dq];
      uint32_t p0 = pack_bf16(v.x, v.y);
      uint32_t p1 = pack_bf16(v.z, v.w);
      *(uint2*)&KtW[n * 68 + 2 * dq] = make_uint2(p0, p1);
      VtW[dq * 36 + n] = p0;
      VtW[(dq + 32) * 36 + n] = p1;
    }
    asm volatile("s_waitcnt lgkmcnt(0)" ::: "memory");

    f32x4 sa[2][2];
    #pragma unroll
    for (int s = 0; s < 2; ++s)
      #pragma unroll
      for (int t = 0; t < 2; ++t) sa[s][t] = (f32x4){0.f, 0.f, 0.f, 0.f};
    #pragma unroll
    for (int c = 0; c < 4; ++c) {
      FragAB k0, k1;
      uint4 a0 = *(const uint4*)&KtW[l15 * 68 + c * 16 + 4 * g];
      uint4 a1 = *(const uint4*)&KtW[(16 + l15) * 68 + c * 16 + 4 * g];
      k0.u[0] = a0.x; k0.u[1] = a0.y; k0.u[2] = a0.z; k0.u[3] = a0.w;
      k1.u[0] = a1.x; k1.u[1] = a1.y; k1.u[2] = a1.z; k1.u[3] = a1.w;
      sa[0][0] = __builtin_amdgcn_mfma_f32_16x16x32_bf16(k0.v, qf[0][c].v, sa[0][0], 0, 0, 0);
      sa[0][1] = __builtin_amdgcn_mfma_f32_16x16x32_bf16(k1.v, qf[0][c].v, sa[0][1], 0, 0, 0);
      sa[1][0] = __builtin_amdgcn_mfma_f32_16x16x32_bf16(k0.v, qf[1][c].v, sa[1][0], 0, 0, 0);
      sa[1][1] = __builtin_amdgcn_mfma_f32_16x16x32_bf16(k1.v, qf[1][c].v, sa[1][1], 0, 0, 0);
    }

    FragAB pa[2];
    #pragma unroll
    for (int s = 0; s < 2; ++s) {
      #pragma unroll
      for (int t = 0; t < 2; ++t) {
        float p0 = __builtin_amdgcn_exp2f(sa[s][t][0] - MBIAS);
        float p1 = __builtin_amdgcn_exp2f(sa[s][t][1] - MBIAS);
        float p2 = __builtin_amdgcn_exp2f(sa[s][t][2] - MBIAS);
        float p3 = __builtin_amdgcn_exp2f(sa[s][t][3] - MBIAS);
        lsum[s] += (p0 + p1) + (p2 + p3);
        uint32_t ib = rb[s] + (uint32_t)(tile * 32 + t * 16 + 4 * g);
        uint32_t h0, h1, bits;
        threefry2x32_k42(0u, ib + 0u, h0, h1); bits = h0 ^ h1;
        float q0 = (bits < KEEP_LT) ? p0 : 0.0f;
        threefry2x32_k42(0u, ib + 1u, h0, h1); bits = h0 ^ h1;
        float q1 = (bits < KEEP_LT) ? p1 : 0.0f;
        threefry2x32_k42(0u, ib + 2u, h0, h1); bits = h0 ^ h1;
        float q2 = (bits < KEEP_LT) ? p2 : 0.0f;
        threefry2x32_k42(0u, ib + 3u, h0, h1); bits = h0 ^ h1;
        float q3 = (bits < KEEP_LT) ? p3 : 0.0f;
        *(uint2*)&PbW[l15 * 20 + t * 8 + 2 * g] =
            make_uint2(pack_bf16(q0, q1), pack_bf16(q2, q3));
      }
      asm volatile("s_waitcnt lgkmcnt(0)" ::: "memory");
      uint4 pu = *(const uint4*)&PbW[l15 * 20 + 4 * g];
      pa[s].u[0] = pu.x; pa[s].u[1] = pu.y; pa[s].u[2] = pu.z; pa[s].u[3] = pu.w;
    }

    #pragma unroll
    for (int dt = 0; dt < 8; ++dt) {
      int rowp = ((l15 >> 1) & 1) * 32 + 4 * dt + (l15 >> 2);
      const uint32_t* vr = &VtW[rowp * 36 + 8 * g];
      uint4 U0 = *(const uint4*)vr;
      uint4 U1 = *(const uint4*)(vr + 4);
      FragAB vb;
      vb.u[0] = __builtin_amdgcn_perm(U0.y, U0.x, permsel);
      vb.u[1] = __builtin_amdgcn_perm(U0.w, U0.z, permsel);
      vb.u[2] = __builtin_amdgcn_perm(U1.y, U1.x, permsel);
      vb.u[3] = __builtin_amdgcn_perm(U1.w, U1.z, permsel);
      o[0][dt] = __builtin_amdgcn_mfma_f32_16x16x32_bf16(pa[0].v, vb.v, o[0][dt], 0, 0, 0);
      o[1][dt] = __builtin_amdgcn_mfma_f32_16x16x32_bf16(pa[1].v, vb.v, o[1][dt], 0, 0, 0);
    }
  }

  __syncthreads();
  float* EP = (float*)&SMEM[0][0];
  #pragma unroll
  for (int s = 0; s < 2; ++s) {
    #pragma unroll
    for (int dt = 0; dt < 8; ++dt)
      #pragma unroll
      for (int r = 0; r < 4; ++r)
        EP[(((wv * 2 + s) * 8 + dt) * 4 + r) * 64 + lane] = o[s][dt][r];
    EP[16384 + (s * 16 + l15) * 16 + wv * 4 + g] = lsum[s];
  }
  __syncthreads();
  const int s = wv >> 1;
  float scale[4];
  #pragma unroll
  for (int r = 0; r < 4; ++r) {
    const float4* lp = (const float4*)&EP[16384 + (s * 16 + 4 * g + r) * 16];
    float4 A = lp[0], B4 = lp[1], C4 = lp[2], D4 = lp[3];
    float L = ((A.x + A.y) + (A.z + A.w)) + ((B4.x + B4.y) + (B4.z + B4.w)) +
              ((C4.x + C4.y) + (C4.z + C4.w)) + ((D4.x + D4.y) + (D4.z + D4.w));
    scale[r] = 1.0f / (L * 0.8f);
  }
  #pragma unroll
  for (int it = 0; it < 4; ++it) {
    int dt = (wv * 4 + it) & 7;
    #pragma unroll
    for (int r = 0; r < 4; ++r) {
      int base = ((s * 8 + dt) * 4 + r) * 64 + lane;
      float tot = EP[base] + EP[base + 4096] + EP[base + 8192] + EP[base + 12288];
      out[((size_t)b * 2048 + m0 + s * 16 + 4 * g + r) * 128 + dt * 16 + l15] =
          tot * scale[r];
    }
  }
}

extern "C" void kernel_launch(void* const* d_in, const int* in_sizes, int n_in,
                              void* d_out, int out_size, void* d_ws, size_t ws_size,
                              hipStream_t stream) {
  const float* x1 = (const float*)d_in[0];
  const float* x2 = (const float*)d_in[1];
  float* out = (float*)d_out;
  if (d_ws != nullptr && ws_size >= (size_t)8 * 1024 * 1024) {
    uint4* KF = (uint4*)d_ws;
    uint4* VF = KF + 262144;   // +4MB
    prep_kernel<<<dim3(64, 8, 1), dim3(256, 1, 1), 0, stream>>>(x2, KF, VF);
    attn2_kernel<<<dim3(128, 8, 1), dim3(256, 1, 1), 0, stream>>>(x1, KF, VF, out);
  } else {
    attn_kernel<<<dim3(64, 8, 1), dim3(256, 1, 1), 0, stream>>>(x1, x2, out);
  }
}